// Round 1
// baseline (2006.925 us; speedup 1.0000x reference)
//
#include <hip/hip_runtime.h>
#include <hip/hip_bf16.h>
#include <stdint.h>

#define T_TOK 4096
#define H_DIM 1024
#define I_DIM 2816
#define E_NUM 8
#define BK 64

typedef float f32x4 __attribute__((ext_vector_type(4)));
typedef __bf16 bf16x8 __attribute__((ext_vector_type(8)));
typedef __bf16 bf16x4 __attribute__((ext_vector_type(4)));

__device__ __forceinline__ void gload_lds16(const void* g, void* l) {
    __builtin_amdgcn_global_load_lds((const __attribute__((address_space(1))) void*)g,
                                     (__attribute__((address_space(3))) void*)l, 16, 0, 0);
}

__device__ __forceinline__ bf16x8 cvt8(float4 a, float4 b) {
    bf16x8 r;
    r[0] = (__bf16)a.x; r[1] = (__bf16)a.y; r[2] = (__bf16)a.z; r[3] = (__bf16)a.w;
    r[4] = (__bf16)b.x; r[5] = (__bf16)b.y; r[6] = (__bf16)b.z; r[7] = (__bf16)b.w;
    return r;
}

// ---------------- x: f32 -> bf16 ----------------
__global__ __launch_bounds__(256) void k_convert_x(const float* __restrict__ x,
                                                   __bf16* __restrict__ xbf) {
    int idx = blockIdx.x * 256 + threadIdx.x;
    float4 v = ((const float4*)x)[idx];
    bf16x4 o;
    o[0] = (__bf16)v.x; o[1] = (__bf16)v.y; o[2] = (__bf16)v.z; o[3] = (__bf16)v.w;
    ((bf16x4*)xbf)[idx] = o;
}

// ---------------- router: logits, top-2, softmax, scatter to expert lists ----------------
__global__ __launch_bounds__(256) void k_router(const float* __restrict__ x,
                                                const float* __restrict__ rw,
                                                int* __restrict__ list,
                                                float* __restrict__ wslot,
                                                int* __restrict__ counts) {
    int tid = threadIdx.x;
    int wid = tid >> 6, lane = tid & 63;
    int t = blockIdx.x * 4 + wid;

    float acc[E_NUM];
#pragma unroll
    for (int e = 0; e < E_NUM; ++e) acc[e] = 0.f;

    const float4* x4 = (const float4*)(x + (size_t)t * H_DIM);
    const float4* r4 = (const float4*)rw;
#pragma unroll
    for (int j = 0; j < 4; ++j) {
        float4 xv = x4[j * 64 + lane];
#pragma unroll
        for (int e = 0; e < E_NUM; ++e) {
            float4 wv = r4[e * 256 + j * 64 + lane];
            acc[e] += xv.x * wv.x + xv.y * wv.y + xv.z * wv.z + xv.w * wv.w;
        }
    }
#pragma unroll
    for (int s = 1; s < 64; s <<= 1) {
#pragma unroll
        for (int e = 0; e < E_NUM; ++e) acc[e] += __shfl_xor(acc[e], s, 64);
    }
    if (lane == 0) {
        float best = -1e30f; int be = 0;
#pragma unroll
        for (int e = 0; e < E_NUM; ++e) if (acc[e] > best) { best = acc[e]; be = e; }
        float sec = -1e30f; int se = 0;
#pragma unroll
        for (int e = 0; e < E_NUM; ++e) if (e != be && acc[e] > sec) { sec = acc[e]; se = e; }
        float d = __expf(sec - best);
        float w1 = 1.f / (1.f + d);
        float w2 = d / (1.f + d);
        int p1 = atomicAdd(&counts[be], 1);
        list[be * T_TOK + p1] = 2 * t;
        wslot[2 * t] = w1;
        int p2 = atomicAdd(&counts[se], 1);
        list[se * T_TOK + p2] = 2 * t + 1;
        wslot[2 * t + 1] = w2;
    }
}

// ---------------- GEMM1: h[slot, i] = silu(x@Wg^T) * (x@Wu^T), gathered rows ----------------
__global__ __launch_bounds__(256) void k_gemm1(const __bf16* __restrict__ xbf,
                                               const float* __restrict__ Wg,
                                               const float* __restrict__ Wu,
                                               const int* __restrict__ list,
                                               const int* __restrict__ counts,
                                               __bf16* __restrict__ hbuf) {
    __shared__ __attribute__((aligned(16))) unsigned char lA[128 * BK * 2];
    __shared__ __attribute__((aligned(16))) unsigned char lBg[128 * BK * 2];
    __shared__ __attribute__((aligned(16))) unsigned char lBu[128 * BK * 2];
    __shared__ int slots[128];

    const int e = blockIdx.z;
    const int cnt = counts[e];
    const int tm = blockIdx.x;
    if (tm * 128 >= cnt) return;
    const int tn = blockIdx.y;
    const int tid = threadIdx.x;
    const int lane = tid & 63;
    const int wid = tid >> 6;
    const int wm = wid >> 1, wn = wid & 1;

    if (tid < 128) {
        int p = tm * 128 + tid;
        int pc = p < cnt ? p : cnt - 1;
        slots[tid] = list[e * T_TOK + pc];
    }
    __syncthreads();

    // A-staging addresses (source pre-swizzled so linear LDS + swizzled read match)
    const char* aSrc[4];
    void* aDst[4];
    {
        const char* xc = (const char*)xbf;
        int colb = (tid & 7) * 16;
#pragma unroll
        for (int r = 0; r < 4; ++r) {
            int row = r * 32 + (tid >> 3);
            int lcolb = colb ^ ((row & 7) << 4);
            int tok = slots[row] >> 1;
            aSrc[r] = xc + (size_t)tok * (H_DIM * 2) + lcolb;
            aDst[r] = (void*)(lA + (r * 256 + (tid & ~63)) * 16);
        }
    }

    const int brow = tid >> 1, bhalf = tid & 1;
    const size_t wrowbase = ((size_t)e * I_DIM + (size_t)tn * 128 + brow) * H_DIM + bhalf * 32;
    const float* srcg = Wg + wrowbase;
    const float* srcu = Wu + wrowbase;
    const int bswz = (brow & 7) << 4;
    const int blbase = brow * 128 + bhalf * 64;

    const f32x4 zero = {0.f, 0.f, 0.f, 0.f};
    f32x4 accg[4][4], accu[4][4];
#pragma unroll
    for (int i = 0; i < 4; ++i)
#pragma unroll
        for (int j = 0; j < 4; ++j) { accg[i][j] = zero; accu[i][j] = zero; }

    for (int kt = 0; kt < H_DIM / BK; ++kt) {
#pragma unroll
        for (int r = 0; r < 4; ++r)
            gload_lds16(aSrc[r] + kt * (BK * 2), aDst[r]);

        const float4* pg = (const float4*)(srcg + kt * BK);
        const float4* pu = (const float4*)(srcu + kt * BK);
#pragma unroll
        for (int q = 0; q < 4; ++q) {
            float4 a = pg[q * 2], b = pg[q * 2 + 1];
            *(bf16x8*)(lBg + ((blbase + q * 16) ^ bswz)) = cvt8(a, b);
        }
#pragma unroll
        for (int q = 0; q < 4; ++q) {
            float4 a = pu[q * 2], b = pu[q * 2 + 1];
            *(bf16x8*)(lBu + ((blbase + q * 16) ^ bswz)) = cvt8(a, b);
        }
        __syncthreads();

#pragma unroll
        for (int kk = 0; kk < 2; ++kk) {
            bf16x8 av[4], bg[4], bu[4];
#pragma unroll
            for (int mi = 0; mi < 4; ++mi) {
                int row = wm * 64 + mi * 16 + (lane & 15);
                int byte = (row * 128 + kk * 64 + (lane >> 4) * 16) ^ ((row & 7) << 4);
                av[mi] = *(const bf16x8*)(lA + byte);
            }
#pragma unroll
            for (int ni = 0; ni < 4; ++ni) {
                int row = wn * 64 + ni * 16 + (lane & 15);
                int byte = (row * 128 + kk * 64 + (lane >> 4) * 16) ^ ((row & 7) << 4);
                bg[ni] = *(const bf16x8*)(lBg + byte);
                bu[ni] = *(const bf16x8*)(lBu + byte);
            }
#pragma unroll
            for (int mi = 0; mi < 4; ++mi)
#pragma unroll
                for (int ni = 0; ni < 4; ++ni) {
                    accg[mi][ni] = __builtin_amdgcn_mfma_f32_16x16x32_bf16(av[mi], bg[ni], accg[mi][ni], 0, 0, 0);
                    accu[mi][ni] = __builtin_amdgcn_mfma_f32_16x16x32_bf16(av[mi], bu[ni], accu[mi][ni], 0, 0, 0);
                }
        }
        __syncthreads();
    }

#pragma unroll
    for (int mi = 0; mi < 4; ++mi) {
        int rowb = wm * 64 + mi * 16 + ((lane >> 4) << 2);
#pragma unroll
        for (int ni = 0; ni < 4; ++ni) {
            int col = tn * 128 + wn * 64 + ni * 16 + (lane & 15);
#pragma unroll
            for (int r = 0; r < 4; ++r) {
                int row = rowb + r;
                if (tm * 128 + row < cnt) {
                    float g = accg[mi][ni][r];
                    float u = accu[mi][ni][r];
                    float hv = (g / (1.f + __expf(-g))) * u;
                    hbuf[(size_t)slots[row] * I_DIM + col] = (__bf16)hv;
                }
            }
        }
    }
}

// ---------------- GEMM2: out[t, :] += w * (h[slot, :] @ Wd[e]^T) ----------------
__global__ __launch_bounds__(256) void k_gemm2(const __bf16* __restrict__ hbuf,
                                               const float* __restrict__ Wd,
                                               const int* __restrict__ list,
                                               const int* __restrict__ counts,
                                               const float* __restrict__ wslot,
                                               float* __restrict__ out) {
    __shared__ __attribute__((aligned(16))) unsigned char lA[128 * BK * 2];
    __shared__ __attribute__((aligned(16))) unsigned char lB[128 * BK * 2];
    __shared__ int slots[128];
    __shared__ float wr[128];

    const int e = blockIdx.z;
    const int cnt = counts[e];
    const int tm = blockIdx.x;
    if (tm * 128 >= cnt) return;
    const int tn = blockIdx.y;
    const int tid = threadIdx.x;
    const int lane = tid & 63;
    const int wid = tid >> 6;
    const int wm = wid >> 1, wn = wid & 1;

    if (tid < 128) {
        int p = tm * 128 + tid;
        int pc = p < cnt ? p : cnt - 1;
        int s = list[e * T_TOK + pc];
        slots[tid] = s;
        wr[tid] = wslot[s];
    }
    __syncthreads();

    const char* aSrc[4];
    void* aDst[4];
    {
        const char* hc = (const char*)hbuf;
        int colb = (tid & 7) * 16;
#pragma unroll
        for (int r = 0; r < 4; ++r) {
            int row = r * 32 + (tid >> 3);
            int lcolb = colb ^ ((row & 7) << 4);
            aSrc[r] = hc + (size_t)slots[row] * (I_DIM * 2) + lcolb;
            aDst[r] = (void*)(lA + (r * 256 + (tid & ~63)) * 16);
        }
    }

    const int brow = tid >> 1, bhalf = tid & 1;
    const float* srcb = Wd + ((size_t)e * H_DIM + (size_t)tn * 128 + brow) * I_DIM + bhalf * 32;
    const int bswz = (brow & 7) << 4;
    const int blbase = brow * 128 + bhalf * 64;

    const f32x4 zero = {0.f, 0.f, 0.f, 0.f};
    f32x4 acc[4][4];
#pragma unroll
    for (int i = 0; i < 4; ++i)
#pragma unroll
        for (int j = 0; j < 4; ++j) acc[i][j] = zero;

    for (int kt = 0; kt < I_DIM / BK; ++kt) {
#pragma unroll
        for (int r = 0; r < 4; ++r)
            gload_lds16(aSrc[r] + kt * (BK * 2), aDst[r]);

        const float4* pb = (const float4*)(srcb + kt * BK);
#pragma unroll
        for (int q = 0; q < 4; ++q) {
            float4 a = pb[q * 2], b = pb[q * 2 + 1];
            *(bf16x8*)(lB + ((blbase + q * 16) ^ bswz)) = cvt8(a, b);
        }
        __syncthreads();

#pragma unroll
        for (int kk = 0; kk < 2; ++kk) {
            bf16x8 av[4], bv[4];
#pragma unroll
            for (int mi = 0; mi < 4; ++mi) {
                int row = wm * 64 + mi * 16 + (lane & 15);
                int byte = (row * 128 + kk * 64 + (lane >> 4) * 16) ^ ((row & 7) << 4);
                av[mi] = *(const bf16x8*)(lA + byte);
            }
#pragma unroll
            for (int ni = 0; ni < 4; ++ni) {
                int row = wn * 64 + ni * 16 + (lane & 15);
                int byte = (row * 128 + kk * 64 + (lane >> 4) * 16) ^ ((row & 7) << 4);
                bv[ni] = *(const bf16x8*)(lB + byte);
            }
#pragma unroll
            for (int mi = 0; mi < 4; ++mi)
#pragma unroll
                for (int ni = 0; ni < 4; ++ni)
                    acc[mi][ni] = __builtin_amdgcn_mfma_f32_16x16x32_bf16(av[mi], bv[ni], acc[mi][ni], 0, 0, 0);
        }
        __syncthreads();
    }

#pragma unroll
    for (int mi = 0; mi < 4; ++mi) {
        int rowb = wm * 64 + mi * 16 + ((lane >> 4) << 2);
#pragma unroll
        for (int ni = 0; ni < 4; ++ni) {
            int col = tn * 128 + wn * 64 + ni * 16 + (lane & 15);
#pragma unroll
            for (int r = 0; r < 4; ++r) {
                int row = rowb + r;
                if (tm * 128 + row < cnt) {
                    int t = slots[row] >> 1;
                    atomicAdd(out + (size_t)t * H_DIM + col, acc[mi][ni][r] * wr[row]);
                }
            }
        }
    }
}

extern "C" void kernel_launch(void* const* d_in, const int* in_sizes, int n_in,
                              void* d_out, int out_size, void* d_ws, size_t ws_size,
                              hipStream_t stream) {
    const float* x  = (const float*)d_in[0];
    const float* rw = (const float*)d_in[1];
    const float* Wg = (const float*)d_in[2];
    const float* Wu = (const float*)d_in[3];
    const float* Wd = (const float*)d_in[4];
    float* out = (float*)d_out;

    char* ws = (char*)d_ws;
    __bf16* xbf   = (__bf16*)(ws);                    // 8,388,608 B
    __bf16* hbuf  = (__bf16*)(ws + 8388608);          // 46,137,344 B
    int*    list  = (int*)(ws + 54525952);            // 131,072 B
    float*  wslot = (float*)(ws + 54657024);          // 32,768 B
    int*    counts= (int*)(ws + 54689792);            // 32 B

    hipMemsetAsync(d_out, 0, (size_t)out_size * sizeof(float), stream);
    hipMemsetAsync(counts, 0, E_NUM * sizeof(int), stream);

    k_convert_x<<<4096, 256, 0, stream>>>(x, xbf);
    k_router<<<T_TOK / 4, 256, 0, stream>>>(x, rw, list, wslot, counts);
    k_gemm1<<<dim3(32, I_DIM / 128, E_NUM), 256, 0, stream>>>(xbf, Wg, Wu, list, counts, hbuf);
    k_gemm2<<<dim3(32, H_DIM / 128, E_NUM), 256, 0, stream>>>(hbuf, Wd, list, counts, wslot, out);
}

// Round 2
// 542.727 us; speedup vs baseline: 3.6979x; 3.6979x over previous
//
#include <hip/hip_runtime.h>
#include <hip/hip_bf16.h>
#include <stdint.h>

#define T_TOK 4096
#define H_DIM 1024
#define I_DIM 2816
#define E_NUM 8
#define BK 64

typedef float f32x4 __attribute__((ext_vector_type(4)));
typedef __bf16 bf16x8 __attribute__((ext_vector_type(8)));
typedef __bf16 bf16x4 __attribute__((ext_vector_type(4)));

__device__ __forceinline__ void gload_lds16(const void* g, void* l) {
    __builtin_amdgcn_global_load_lds((const __attribute__((address_space(1))) void*)g,
                                     (__attribute__((address_space(3))) void*)l, 16, 0, 0);
}

__device__ __forceinline__ bf16x8 cvt8(float4 a, float4 b) {
    bf16x8 r;
    r[0] = (__bf16)a.x; r[1] = (__bf16)a.y; r[2] = (__bf16)a.z; r[3] = (__bf16)a.w;
    r[4] = (__bf16)b.x; r[5] = (__bf16)b.y; r[6] = (__bf16)b.z; r[7] = (__bf16)b.w;
    return r;
}

// ---------------- x: f32 -> bf16 ----------------
__global__ __launch_bounds__(256) void k_convert_x(const float* __restrict__ x,
                                                   __bf16* __restrict__ xbf) {
    int idx = blockIdx.x * 256 + threadIdx.x;
    float4 v = ((const float4*)x)[idx];
    bf16x4 o;
    o[0] = (__bf16)v.x; o[1] = (__bf16)v.y; o[2] = (__bf16)v.z; o[3] = (__bf16)v.w;
    ((bf16x4*)xbf)[idx] = o;
}

// ---------------- router ----------------
__global__ __launch_bounds__(256) void k_router(const float* __restrict__ x,
                                                const float* __restrict__ rw,
                                                int* __restrict__ list,
                                                float* __restrict__ wslot,
                                                int* __restrict__ counts) {
    int tid = threadIdx.x;
    int wid = tid >> 6, lane = tid & 63;
    int t = blockIdx.x * 4 + wid;

    float acc[E_NUM];
#pragma unroll
    for (int e = 0; e < E_NUM; ++e) acc[e] = 0.f;

    const float4* x4 = (const float4*)(x + (size_t)t * H_DIM);
    const float4* r4 = (const float4*)rw;
#pragma unroll
    for (int j = 0; j < 4; ++j) {
        float4 xv = x4[j * 64 + lane];
#pragma unroll
        for (int e = 0; e < E_NUM; ++e) {
            float4 wv = r4[e * 256 + j * 64 + lane];
            acc[e] += xv.x * wv.x + xv.y * wv.y + xv.z * wv.z + xv.w * wv.w;
        }
    }
#pragma unroll
    for (int s = 1; s < 64; s <<= 1) {
#pragma unroll
        for (int e = 0; e < E_NUM; ++e) acc[e] += __shfl_xor(acc[e], s, 64);
    }
    if (lane == 0) {
        float best = -1e30f; int be = 0;
#pragma unroll
        for (int e = 0; e < E_NUM; ++e) if (acc[e] > best) { best = acc[e]; be = e; }
        float sec = -1e30f; int se = 0;
#pragma unroll
        for (int e = 0; e < E_NUM; ++e) if (e != be && acc[e] > sec) { sec = acc[e]; se = e; }
        float d = __expf(sec - best);
        float w1 = 1.f / (1.f + d);
        float w2 = d / (1.f + d);
        int p1 = atomicAdd(&counts[be], 1);
        list[be * T_TOK + p1] = 2 * t;
        wslot[2 * t] = w1;
        int p2 = atomicAdd(&counts[se], 1);
        list[se * T_TOK + p2] = 2 * t + 1;
        wslot[2 * t + 1] = w2;
    }
}

// ---------------- GEMM1: tile 128(M slots) x 64(N of I), BK=64, 8 waves, wave tile 32x32 ----------------
__global__ __launch_bounds__(512, 4) void k_gemm1(const __bf16* __restrict__ xbf,
                                                  const float* __restrict__ Wg,
                                                  const float* __restrict__ Wu,
                                                  const int* __restrict__ list,
                                                  const int* __restrict__ counts,
                                                  __bf16* __restrict__ hbuf) {
    __shared__ __attribute__((aligned(16))) unsigned char lA[2][128 * BK * 2];
    __shared__ __attribute__((aligned(16))) unsigned char lBg[2][64 * BK * 2];
    __shared__ __attribute__((aligned(16))) unsigned char lBu[2][64 * BK * 2];
    __shared__ int slots[128];

    const int lid = blockIdx.x;
    const int e = lid & 7;          // expert pinned to XCD
    const int seq = lid >> 3;
    const int tn = seq >> 5;        // 44 tiles of 64 cols
    const int tm = seq & 31;        // tm-groups temporally adjacent per (e,tn)
    const int cnt = counts[e];
    if (tm * 128 >= cnt) return;
    const int tid = threadIdx.x;
    const int lane = tid & 63;
    const int wid = tid >> 6;
    const int wm = wid >> 1;        // 0..3 : 32 rows each
    const int wn = wid & 1;         // 0..1 : 32 cols each

    if (tid < 128) {
        int p = tm * 128 + tid;
        slots[tid] = list[e * T_TOK + (p < cnt ? p : cnt - 1)];
    }
    __syncthreads();

    // A staging: 128 rows x 64 bf16 (128B/row), 2 gloads/thread, source pre-swizzled
    const char* aSrc[2];
    uint32_t aOff[2];
    {
        int colb = (tid & 7) * 16;
#pragma unroll
        for (int r = 0; r < 2; ++r) {
            int row = r * 64 + (tid >> 3);
            int tok = slots[row] >> 1;
            aSrc[r] = (const char*)xbf + (size_t)tok * (H_DIM * 2) + (colb ^ ((row & 7) << 4));
            aOff[r] = (uint32_t)(row * 128 + colb);
        }
    }
    // B staging: 64 rows x 64 f32 per matrix; thread -> (row=tid>>3, 8 floats at (tid&7)*8)
    const int brow = tid >> 3;
    const int bq = tid & 7;
    const float* srcg = Wg + ((size_t)e * I_DIM + (size_t)tn * 64 + brow) * H_DIM + bq * 8;
    const float* srcu = Wu + ((size_t)e * I_DIM + (size_t)tn * 64 + brow) * H_DIM + bq * 8;
    const uint32_t bOff = (uint32_t)((brow * 128 + bq * 16) ^ ((brow & 7) << 4));

    const f32x4 zero = {0.f, 0.f, 0.f, 0.f};
    f32x4 accg[2][2], accu[2][2];
#pragma unroll
    for (int i = 0; i < 2; ++i)
#pragma unroll
        for (int j = 0; j < 2; ++j) { accg[i][j] = zero; accu[i][j] = zero; }

    // prologue: A(0) in flight, B(0) in regs
    gload_lds16(aSrc[0], &lA[0][aOff[0]]);
    gload_lds16(aSrc[1], &lA[0][aOff[1]]);
    float4 g0 = ((const float4*)srcg)[0], g1 = ((const float4*)srcg)[1];
    float4 u0 = ((const float4*)srcu)[0], u1 = ((const float4*)srcu)[1];

    for (int kt = 0; kt < H_DIM / BK; ++kt) {
        const int cur = kt & 1, nxt = cur ^ 1;
        // write B(kt) to LDS
        *(bf16x8*)&lBg[cur][bOff] = cvt8(g0, g1);
        *(bf16x8*)&lBu[cur][bOff] = cvt8(u0, u1);
        __syncthreads();   // drains: A(kt) gload (issued last iter) + B ds_writes
        if (kt + 1 < H_DIM / BK) {
            gload_lds16(aSrc[0] + (kt + 1) * 128, &lA[nxt][aOff[0]]);
            gload_lds16(aSrc[1] + (kt + 1) * 128, &lA[nxt][aOff[1]]);
            const float4* pg = (const float4*)(srcg + (kt + 1) * BK);
            const float4* pu = (const float4*)(srcu + (kt + 1) * BK);
            g0 = pg[0]; g1 = pg[1]; u0 = pu[0]; u1 = pu[1];
        }
#pragma unroll
        for (int kk = 0; kk < 2; ++kk) {
            bf16x8 av[2], bg[2], bu[2];
#pragma unroll
            for (int mi = 0; mi < 2; ++mi) {
                int row = wm * 32 + mi * 16 + (lane & 15);
                int byte = (row * 128 + kk * 64 + (lane >> 4) * 16) ^ ((row & 7) << 4);
                av[mi] = *(const bf16x8*)&lA[cur][byte];
            }
#pragma unroll
            for (int ni = 0; ni < 2; ++ni) {
                int row = wn * 32 + ni * 16 + (lane & 15);
                int byte = (row * 128 + kk * 64 + (lane >> 4) * 16) ^ ((row & 7) << 4);
                bg[ni] = *(const bf16x8*)&lBg[cur][byte];
                bu[ni] = *(const bf16x8*)&lBu[cur][byte];
            }
#pragma unroll
            for (int mi = 0; mi < 2; ++mi)
#pragma unroll
                for (int ni = 0; ni < 2; ++ni) {
                    accg[mi][ni] = __builtin_amdgcn_mfma_f32_16x16x32_bf16(av[mi], bg[ni], accg[mi][ni], 0, 0, 0);
                    accu[mi][ni] = __builtin_amdgcn_mfma_f32_16x16x32_bf16(av[mi], bu[ni], accu[mi][ni], 0, 0, 0);
                }
        }
        // no trailing barrier: next iter writes the OTHER B buffer; A gload targets the OTHER A buffer
    }

#pragma unroll
    for (int mi = 0; mi < 2; ++mi) {
#pragma unroll
        for (int ni = 0; ni < 2; ++ni) {
            int col = tn * 64 + wn * 32 + ni * 16 + (lane & 15);
#pragma unroll
            for (int r = 0; r < 4; ++r) {
                int trow = wm * 32 + mi * 16 + ((lane >> 4) << 2) + r;
                if (tm * 128 + trow < cnt) {
                    float g = accg[mi][ni][r];
                    float u = accu[mi][ni][r];
                    float hv = (g / (1.f + __expf(-g))) * u;
                    hbuf[(size_t)slots[trow] * I_DIM + col] = (__bf16)hv;
                }
            }
        }
    }
}

// ---------------- GEMM2: tile 128(M slots) x 128(N of H), BK=64, 8 waves, wave tile 32x64 ----------------
__global__ __launch_bounds__(512, 4) void k_gemm2(const __bf16* __restrict__ hbuf,
                                                  const float* __restrict__ Wd,
                                                  const int* __restrict__ list,
                                                  const int* __restrict__ counts,
                                                  const float* __restrict__ wslot,
                                                  float* __restrict__ out) {
    __shared__ __attribute__((aligned(16))) unsigned char lA[2][128 * BK * 2];
    __shared__ __attribute__((aligned(16))) unsigned char lB[2][128 * BK * 2];
    __shared__ int slots[128];
    __shared__ float wr[128];

    const int lid = blockIdx.x;
    const int e = lid & 7;
    const int seq = lid >> 3;
    const int tn = seq >> 5;        // 8 tiles of 128 cols
    const int tm = seq & 31;
    const int cnt = counts[e];
    if (tm * 128 >= cnt) return;
    const int tid = threadIdx.x;
    const int lane = tid & 63;
    const int wid = tid >> 6;
    const int wm = wid >> 1;        // 0..3 : 32 rows
    const int wn = wid & 1;         // 0..1 : 64 cols

    if (tid < 128) {
        int p = tm * 128 + tid;
        int s = list[e * T_TOK + (p < cnt ? p : cnt - 1)];
        slots[tid] = s;
        wr[tid] = wslot[s];
    }
    __syncthreads();

    const char* aSrc[2];
    uint32_t aOff[2];
    {
        int colb = (tid & 7) * 16;
#pragma unroll
        for (int r = 0; r < 2; ++r) {
            int row = r * 64 + (tid >> 3);
            aSrc[r] = (const char*)hbuf + (size_t)slots[row] * (I_DIM * 2) + (colb ^ ((row & 7) << 4));
            aOff[r] = (uint32_t)(row * 128 + colb);
        }
    }
    // B staging: 128 rows x 64 f32; thread -> (row=tid>>2, 16 floats at (tid&3)*16)
    const int brow = tid >> 2;
    const int bq = tid & 3;
    const float* srcb = Wd + ((size_t)e * H_DIM + (size_t)tn * 128 + brow) * I_DIM + bq * 16;
    const uint32_t bOff0 = (uint32_t)((brow * 128 + bq * 32) ^ ((brow & 7) << 4));
    const uint32_t bOff1 = (uint32_t)((brow * 128 + bq * 32 + 16) ^ ((brow & 7) << 4));

    const f32x4 zero = {0.f, 0.f, 0.f, 0.f};
    f32x4 acc[2][4];
#pragma unroll
    for (int i = 0; i < 2; ++i)
#pragma unroll
        for (int j = 0; j < 4; ++j) acc[i][j] = zero;

    gload_lds16(aSrc[0], &lA[0][aOff[0]]);
    gload_lds16(aSrc[1], &lA[0][aOff[1]]);
    float4 w0 = ((const float4*)srcb)[0], w1 = ((const float4*)srcb)[1];
    float4 w2 = ((const float4*)srcb)[2], w3 = ((const float4*)srcb)[3];

    for (int kt = 0; kt < I_DIM / BK; ++kt) {
        const int cur = kt & 1, nxt = cur ^ 1;
        *(bf16x8*)&lB[cur][bOff0] = cvt8(w0, w1);
        *(bf16x8*)&lB[cur][bOff1] = cvt8(w2, w3);
        __syncthreads();
        if (kt + 1 < I_DIM / BK) {
            gload_lds16(aSrc[0] + (kt + 1) * 128, &lA[nxt][aOff[0]]);
            gload_lds16(aSrc[1] + (kt + 1) * 128, &lA[nxt][aOff[1]]);
            const float4* pb = (const float4*)(srcb + (kt + 1) * BK);
            w0 = pb[0]; w1 = pb[1]; w2 = pb[2]; w3 = pb[3];
        }
#pragma unroll
        for (int kk = 0; kk < 2; ++kk) {
            bf16x8 av[2], bv[4];
#pragma unroll
            for (int mi = 0; mi < 2; ++mi) {
                int row = wm * 32 + mi * 16 + (lane & 15);
                int byte = (row * 128 + kk * 64 + (lane >> 4) * 16) ^ ((row & 7) << 4);
                av[mi] = *(const bf16x8*)&lA[cur][byte];
            }
#pragma unroll
            for (int ni = 0; ni < 4; ++ni) {
                int row = wn * 64 + ni * 16 + (lane & 15);
                int byte = (row * 128 + kk * 64 + (lane >> 4) * 16) ^ ((row & 7) << 4);
                bv[ni] = *(const bf16x8*)&lB[cur][byte];
            }
#pragma unroll
            for (int mi = 0; mi < 2; ++mi)
#pragma unroll
                for (int ni = 0; ni < 4; ++ni)
                    acc[mi][ni] = __builtin_amdgcn_mfma_f32_16x16x32_bf16(av[mi], bv[ni], acc[mi][ni], 0, 0, 0);
        }
    }

#pragma unroll
    for (int mi = 0; mi < 2; ++mi) {
#pragma unroll
        for (int ni = 0; ni < 4; ++ni) {
            int col = tn * 128 + wn * 64 + ni * 16 + (lane & 15);
#pragma unroll
            for (int r = 0; r < 4; ++r) {
                int trow = wm * 32 + mi * 16 + ((lane >> 4) << 2) + r;
                if (tm * 128 + trow < cnt) {
                    int t = slots[trow] >> 1;
                    atomicAdd(out + (size_t)t * H_DIM + col, acc[mi][ni][r] * wr[trow]);
                }
            }
        }
    }
}

extern "C" void kernel_launch(void* const* d_in, const int* in_sizes, int n_in,
                              void* d_out, int out_size, void* d_ws, size_t ws_size,
                              hipStream_t stream) {
    const float* x  = (const float*)d_in[0];
    const float* rw = (const float*)d_in[1];
    const float* Wg = (const float*)d_in[2];
    const float* Wu = (const float*)d_in[3];
    const float* Wd = (const float*)d_in[4];
    float* out = (float*)d_out;

    char* ws = (char*)d_ws;
    __bf16* xbf   = (__bf16*)(ws);                    // 8,388,608 B
    __bf16* hbuf  = (__bf16*)(ws + 8388608);          // 46,137,344 B
    int*    list  = (int*)(ws + 54525952);            // 131,072 B
    float*  wslot = (float*)(ws + 54657024);          // 32,768 B
    int*    counts= (int*)(ws + 54689792);            // 32 B

    hipMemsetAsync(d_out, 0, (size_t)out_size * sizeof(float), stream);
    hipMemsetAsync(counts, 0, E_NUM * sizeof(int), stream);

    k_convert_x<<<4096, 256, 0, stream>>>(x, xbf);
    k_router<<<T_TOK / 4, 256, 0, stream>>>(x, rw, list, wslot, counts);
    // gemm1: lid = ((tn*32 + tm) << 3) | e  -> 8 experts x 44 tn x 32 tm
    k_gemm1<<<8 * 44 * 32, 512, 0, stream>>>(xbf, Wg, Wu, list, counts, hbuf);
    // gemm2: 8 experts x 8 tn x 32 tm
    k_gemm2<<<8 * 8 * 32, 512, 0, stream>>>(hbuf, Wd, list, counts, wslot, out);
}

// Round 3
// 530.789 us; speedup vs baseline: 3.7810x; 1.0225x over previous
//
#include <hip/hip_runtime.h>
#include <hip/hip_bf16.h>
#include <stdint.h>

#define T_TOK 4096
#define H_DIM 1024
#define I_DIM 2816
#define E_NUM 8
#define BK 64

typedef float f32x4 __attribute__((ext_vector_type(4)));
typedef __bf16 bf16x8 __attribute__((ext_vector_type(8)));
typedef __bf16 bf16x4 __attribute__((ext_vector_type(4)));

__device__ __forceinline__ void gload_lds16(const void* g, void* l) {
    __builtin_amdgcn_global_load_lds((const __attribute__((address_space(1))) void*)g,
                                     (__attribute__((address_space(3))) void*)l, 16, 0, 0);
}

__device__ __forceinline__ bf16x8 cvt8(float4 a, float4 b) {
    bf16x8 r;
    r[0] = (__bf16)a.x; r[1] = (__bf16)a.y; r[2] = (__bf16)a.z; r[3] = (__bf16)a.w;
    r[4] = (__bf16)b.x; r[5] = (__bf16)b.y; r[6] = (__bf16)b.z; r[7] = (__bf16)b.w;
    return r;
}

// ---------------- x: f32 -> bf16 ----------------
__global__ __launch_bounds__(256) void k_convert_x(const float* __restrict__ x,
                                                   __bf16* __restrict__ xbf) {
    int idx = blockIdx.x * 256 + threadIdx.x;
    float4 v = ((const float4*)x)[idx];
    bf16x4 o;
    o[0] = (__bf16)v.x; o[1] = (__bf16)v.y; o[2] = (__bf16)v.z; o[3] = (__bf16)v.w;
    ((bf16x4*)xbf)[idx] = o;
}

// ---------------- router ----------------
__global__ __launch_bounds__(256) void k_router(const float* __restrict__ x,
                                                const float* __restrict__ rw,
                                                int* __restrict__ list,
                                                float* __restrict__ wslot,
                                                int* __restrict__ counts) {
    int tid = threadIdx.x;
    int wid = tid >> 6, lane = tid & 63;
    int t = blockIdx.x * 4 + wid;

    float acc[E_NUM];
#pragma unroll
    for (int e = 0; e < E_NUM; ++e) acc[e] = 0.f;

    const float4* x4 = (const float4*)(x + (size_t)t * H_DIM);
    const float4* r4 = (const float4*)rw;
#pragma unroll
    for (int j = 0; j < 4; ++j) {
        float4 xv = x4[j * 64 + lane];
#pragma unroll
        for (int e = 0; e < E_NUM; ++e) {
            float4 wv = r4[e * 256 + j * 64 + lane];
            acc[e] += xv.x * wv.x + xv.y * wv.y + xv.z * wv.z + xv.w * wv.w;
        }
    }
#pragma unroll
    for (int s = 1; s < 64; s <<= 1) {
#pragma unroll
        for (int e = 0; e < E_NUM; ++e) acc[e] += __shfl_xor(acc[e], s, 64);
    }
    if (lane == 0) {
        float best = -1e30f; int be = 0;
#pragma unroll
        for (int e = 0; e < E_NUM; ++e) if (acc[e] > best) { best = acc[e]; be = e; }
        float sec = -1e30f; int se = 0;
#pragma unroll
        for (int e = 0; e < E_NUM; ++e) if (e != be && acc[e] > sec) { sec = acc[e]; se = e; }
        float d = __expf(sec - best);
        float w1 = 1.f / (1.f + d);
        float w2 = d / (1.f + d);
        int p1 = atomicAdd(&counts[be], 1);
        list[be * T_TOK + p1] = 2 * t;
        wslot[2 * t] = w1;
        int p2 = atomicAdd(&counts[se], 1);
        list[se * T_TOK + p2] = 2 * t + 1;
        wslot[2 * t + 1] = w2;
    }
}

// ---------------- GEMM1: tile 128(M) x 64(N of I), BK=64, 8 waves, counted-vmcnt pipeline ----------------
__global__ __launch_bounds__(512, 4) void k_gemm1(const __bf16* __restrict__ xbf,
                                                  const float* __restrict__ Wg,
                                                  const float* __restrict__ Wu,
                                                  const int* __restrict__ list,
                                                  const int* __restrict__ counts,
                                                  __bf16* __restrict__ hbuf) {
    __shared__ __attribute__((aligned(16))) unsigned char lA[2][128 * BK * 2];
    __shared__ __attribute__((aligned(16))) unsigned char lBg[2][64 * BK * 2];
    __shared__ __attribute__((aligned(16))) unsigned char lBu[2][64 * BK * 2];
    __shared__ int slots[128];

    const int lid = blockIdx.x;
    const int e = lid & 7;          // expert pinned to XCD
    const int seq = lid >> 3;
    const int tn = seq >> 5;        // 44 tiles of 64 cols
    const int tm = seq & 31;
    const int cnt = counts[e];
    if (tm * 128 >= cnt) return;
    const int tid = threadIdx.x;
    const int lane = tid & 63;
    const int wid = tid >> 6;
    const int wm = wid >> 1;        // 4 x 32 rows
    const int wn = wid & 1;         // 2 x 32 cols

    if (tid < 128) {
        int p = tm * 128 + tid;
        slots[tid] = list[e * T_TOK + (p < cnt ? p : cnt - 1)];
    }
    __syncthreads();   // full drain: vmcnt baseline = 0 for every wave

    const char* aSrc[2];
    uint32_t aOff[2];
    {
        int colb = (tid & 7) * 16;
#pragma unroll
        for (int r = 0; r < 2; ++r) {
            int row = r * 64 + (tid >> 3);
            int tok = slots[row] >> 1;
            aSrc[r] = (const char*)xbf + (size_t)tok * (H_DIM * 2) + (colb ^ ((row & 7) << 4));
            aOff[r] = (uint32_t)(row * 128 + colb);
        }
    }
    const int brow = tid >> 3;
    const int bq = tid & 7;
    const float* srcg = Wg + ((size_t)e * I_DIM + (size_t)tn * 64 + brow) * H_DIM + bq * 8;
    const float* srcu = Wu + ((size_t)e * I_DIM + (size_t)tn * 64 + brow) * H_DIM + bq * 8;
    const uint32_t bOff = (uint32_t)((brow * 128 + bq * 16) ^ ((brow & 7) << 4));

    const f32x4 zero = {0.f, 0.f, 0.f, 0.f};
    f32x4 accg[2][2], accu[2][2];
#pragma unroll
    for (int i = 0; i < 2; ++i)
#pragma unroll
        for (int j = 0; j < 2; ++j) { accg[i][j] = zero; accu[i][j] = zero; }

    // prologue: 6 VMEM in flight (2 gload_lds A(0) + 4 B(0) reg loads)
    gload_lds16(aSrc[0], &lA[0][aOff[0]]);
    gload_lds16(aSrc[1], &lA[0][aOff[1]]);
    float4 g0 = ((const float4*)srcg)[0], g1 = ((const float4*)srcg)[1];
    float4 u0 = ((const float4*)srcu)[0], u1 = ((const float4*)srcu)[1];

    const int NT = H_DIM / BK;
    for (int kt = 0; kt < NT; ++kt) {
        const int cur = kt & 1, nxt = cur ^ 1;
        float4 ng0, ng1, nu0, nu1;
        const bool pf = (kt + 1 < NT);
        if (pf) {
            gload_lds16(aSrc[0] + (kt + 1) * 128, &lA[nxt][aOff[0]]);
            gload_lds16(aSrc[1] + (kt + 1) * 128, &lA[nxt][aOff[1]]);
            const float4* pg = (const float4*)(srcg + (kt + 1) * BK);
            const float4* pu = (const float4*)(srcu + (kt + 1) * BK);
            ng0 = pg[0]; ng1 = pg[1]; nu0 = pu[0]; nu1 = pu[1];
        }
        __builtin_amdgcn_sched_barrier(0);
        if (pf) { asm volatile("s_waitcnt vmcnt(6)" ::: "memory"); }
        else    { asm volatile("s_waitcnt vmcnt(0)" ::: "memory"); }
        __builtin_amdgcn_sched_barrier(0);
        // B(kt) regs retired (and A(kt) gloads landed in LDS: issued earlier, in-order retire)
        *(bf16x8*)&lBg[cur][bOff] = cvt8(g0, g1);
        *(bf16x8*)&lBu[cur][bOff] = cvt8(u0, u1);
        asm volatile("s_waitcnt lgkmcnt(0)" ::: "memory");
        __builtin_amdgcn_sched_barrier(0);
        __builtin_amdgcn_s_barrier();
        __builtin_amdgcn_sched_barrier(0);
#pragma unroll
        for (int kk = 0; kk < 2; ++kk) {
            bf16x8 av[2], bg[2], bu[2];
#pragma unroll
            for (int mi = 0; mi < 2; ++mi) {
                int row = wm * 32 + mi * 16 + (lane & 15);
                int byte = (row * 128 + kk * 64 + (lane >> 4) * 16) ^ ((row & 7) << 4);
                av[mi] = *(const bf16x8*)&lA[cur][byte];
            }
#pragma unroll
            for (int ni = 0; ni < 2; ++ni) {
                int row = wn * 32 + ni * 16 + (lane & 15);
                int byte = (row * 128 + kk * 64 + (lane >> 4) * 16) ^ ((row & 7) << 4);
                bg[ni] = *(const bf16x8*)&lBg[cur][byte];
                bu[ni] = *(const bf16x8*)&lBu[cur][byte];
            }
#pragma unroll
            for (int mi = 0; mi < 2; ++mi)
#pragma unroll
                for (int ni = 0; ni < 2; ++ni) {
                    accg[mi][ni] = __builtin_amdgcn_mfma_f32_16x16x32_bf16(av[mi], bg[ni], accg[mi][ni], 0, 0, 0);
                    accu[mi][ni] = __builtin_amdgcn_mfma_f32_16x16x32_bf16(av[mi], bu[ni], accu[mi][ni], 0, 0, 0);
                }
        }
        __builtin_amdgcn_sched_barrier(0);
        __builtin_amdgcn_s_barrier();   // WAR guard: next iter's gload_lds overwrites lA[cur]
        __builtin_amdgcn_sched_barrier(0);
        if (pf) { g0 = ng0; g1 = ng1; u0 = nu0; u1 = nu1; }
    }

#pragma unroll
    for (int mi = 0; mi < 2; ++mi) {
#pragma unroll
        for (int ni = 0; ni < 2; ++ni) {
            int col = tn * 64 + wn * 32 + ni * 16 + (lane & 15);
#pragma unroll
            for (int r = 0; r < 4; ++r) {
                int trow = wm * 32 + mi * 16 + ((lane >> 4) << 2) + r;
                if (tm * 128 + trow < cnt) {
                    float g = accg[mi][ni][r];
                    float u = accu[mi][ni][r];
                    float hv = (g / (1.f + __expf(-g))) * u;
                    hbuf[(size_t)slots[trow] * I_DIM + col] = (__bf16)hv;
                }
            }
        }
    }
}

// ---------------- GEMM2: tile 128(M) x 128(N of H), BK=64, 8 waves, counted-vmcnt pipeline ----------------
__global__ __launch_bounds__(512, 4) void k_gemm2(const __bf16* __restrict__ hbuf,
                                                  const float* __restrict__ Wd,
                                                  const int* __restrict__ list,
                                                  const int* __restrict__ counts,
                                                  const float* __restrict__ wslot,
                                                  float* __restrict__ out) {
    __shared__ __attribute__((aligned(16))) unsigned char lA[2][128 * BK * 2];
    __shared__ __attribute__((aligned(16))) unsigned char lB[2][128 * BK * 2];
    __shared__ int slots[128];
    __shared__ float wr[128];

    const int lid = blockIdx.x;
    const int e = lid & 7;
    const int seq = lid >> 3;
    const int tn = seq >> 5;        // 8 tiles of 128 cols
    const int tm = seq & 31;
    const int cnt = counts[e];
    if (tm * 128 >= cnt) return;
    const int tid = threadIdx.x;
    const int lane = tid & 63;
    const int wid = tid >> 6;
    const int wm = wid >> 1;        // 4 x 32 rows
    const int wn = wid & 1;         // 2 x 64 cols

    if (tid < 128) {
        int p = tm * 128 + tid;
        int s = list[e * T_TOK + (p < cnt ? p : cnt - 1)];
        slots[tid] = s;
        wr[tid] = wslot[s];
    }
    __syncthreads();   // drain

    const char* aSrc[2];
    uint32_t aOff[2];
    {
        int colb = (tid & 7) * 16;
#pragma unroll
        for (int r = 0; r < 2; ++r) {
            int row = r * 64 + (tid >> 3);
            aSrc[r] = (const char*)hbuf + (size_t)slots[row] * (I_DIM * 2) + (colb ^ ((row & 7) << 4));
            aOff[r] = (uint32_t)(row * 128 + colb);
        }
    }
    const int brow = tid >> 2;
    const int bq = tid & 3;
    const float* srcb = Wd + ((size_t)e * H_DIM + (size_t)tn * 128 + brow) * I_DIM + bq * 16;
    const uint32_t bOff0 = (uint32_t)((brow * 128 + bq * 32) ^ ((brow & 7) << 4));
    const uint32_t bOff1 = (uint32_t)((brow * 128 + bq * 32 + 16) ^ ((brow & 7) << 4));

    const f32x4 zero = {0.f, 0.f, 0.f, 0.f};
    f32x4 acc[2][4];
#pragma unroll
    for (int i = 0; i < 2; ++i)
#pragma unroll
        for (int j = 0; j < 4; ++j) acc[i][j] = zero;

    gload_lds16(aSrc[0], &lA[0][aOff[0]]);
    gload_lds16(aSrc[1], &lA[0][aOff[1]]);
    float4 w0 = ((const float4*)srcb)[0], w1 = ((const float4*)srcb)[1];
    float4 w2 = ((const float4*)srcb)[2], w3 = ((const float4*)srcb)[3];

    const int NT = I_DIM / BK;
    for (int kt = 0; kt < NT; ++kt) {
        const int cur = kt & 1, nxt = cur ^ 1;
        float4 nw0, nw1, nw2, nw3;
        const bool pf = (kt + 1 < NT);
        if (pf) {
            gload_lds16(aSrc[0] + (kt + 1) * 128, &lA[nxt][aOff[0]]);
            gload_lds16(aSrc[1] + (kt + 1) * 128, &lA[nxt][aOff[1]]);
            const float4* pb = (const float4*)(srcb + (kt + 1) * BK);
            nw0 = pb[0]; nw1 = pb[1]; nw2 = pb[2]; nw3 = pb[3];
        }
        __builtin_amdgcn_sched_barrier(0);
        if (pf) { asm volatile("s_waitcnt vmcnt(6)" ::: "memory"); }
        else    { asm volatile("s_waitcnt vmcnt(0)" ::: "memory"); }
        __builtin_amdgcn_sched_barrier(0);
        *(bf16x8*)&lB[cur][bOff0] = cvt8(w0, w1);
        *(bf16x8*)&lB[cur][bOff1] = cvt8(w2, w3);
        asm volatile("s_waitcnt lgkmcnt(0)" ::: "memory");
        __builtin_amdgcn_sched_barrier(0);
        __builtin_amdgcn_s_barrier();
        __builtin_amdgcn_sched_barrier(0);
#pragma unroll
        for (int kk = 0; kk < 2; ++kk) {
            bf16x8 av[2], bv[4];
#pragma unroll
            for (int mi = 0; mi < 2; ++mi) {
                int row = wm * 32 + mi * 16 + (lane & 15);
                int byte = (row * 128 + kk * 64 + (lane >> 4) * 16) ^ ((row & 7) << 4);
                av[mi] = *(const bf16x8*)&lA[cur][byte];
            }
#pragma unroll
            for (int ni = 0; ni < 4; ++ni) {
                int row = wn * 64 + ni * 16 + (lane & 15);
                int byte = (row * 128 + kk * 64 + (lane >> 4) * 16) ^ ((row & 7) << 4);
                bv[ni] = *(const bf16x8*)&lB[cur][byte];
            }
#pragma unroll
            for (int mi = 0; mi < 2; ++mi)
#pragma unroll
                for (int ni = 0; ni < 4; ++ni)
                    acc[mi][ni] = __builtin_amdgcn_mfma_f32_16x16x32_bf16(av[mi], bv[ni], acc[mi][ni], 0, 0, 0);
        }
        __builtin_amdgcn_sched_barrier(0);
        __builtin_amdgcn_s_barrier();
        __builtin_amdgcn_sched_barrier(0);
        if (pf) { w0 = nw0; w1 = nw1; w2 = nw2; w3 = nw3; }
    }

#pragma unroll
    for (int mi = 0; mi < 2; ++mi) {
#pragma unroll
        for (int ni = 0; ni < 4; ++ni) {
            int col = tn * 128 + wn * 64 + ni * 16 + (lane & 15);
#pragma unroll
            for (int r = 0; r < 4; ++r) {
                int trow = wm * 32 + mi * 16 + ((lane >> 4) << 2) + r;
                if (tm * 128 + trow < cnt) {
                    int t = slots[trow] >> 1;
                    atomicAdd(out + (size_t)t * H_DIM + col, acc[mi][ni][r] * wr[trow]);
                }
            }
        }
    }
}

extern "C" void kernel_launch(void* const* d_in, const int* in_sizes, int n_in,
                              void* d_out, int out_size, void* d_ws, size_t ws_size,
                              hipStream_t stream) {
    const float* x  = (const float*)d_in[0];
    const float* rw = (const float*)d_in[1];
    const float* Wg = (const float*)d_in[2];
    const float* Wu = (const float*)d_in[3];
    const float* Wd = (const float*)d_in[4];
    float* out = (float*)d_out;

    char* ws = (char*)d_ws;
    __bf16* xbf   = (__bf16*)(ws);                    // 8,388,608 B
    __bf16* hbuf  = (__bf16*)(ws + 8388608);          // 46,137,344 B
    int*    list  = (int*)(ws + 54525952);            // 131,072 B
    float*  wslot = (float*)(ws + 54657024);          // 32,768 B
    int*    counts= (int*)(ws + 54689792);            // 32 B

    hipMemsetAsync(d_out, 0, (size_t)out_size * sizeof(float), stream);
    hipMemsetAsync(counts, 0, E_NUM * sizeof(int), stream);

    k_convert_x<<<4096, 256, 0, stream>>>(x, xbf);
    k_router<<<T_TOK / 4, 256, 0, stream>>>(x, rw, list, wslot, counts);
    k_gemm1<<<8 * 44 * 32, 512, 0, stream>>>(xbf, Wg, Wu, list, counts, hbuf);
    k_gemm2<<<8 * 8 * 32, 512, 0, stream>>>(hbuf, Wd, list, counts, wslot, out);
}

// Round 4
// 460.771 us; speedup vs baseline: 4.3556x; 1.1520x over previous
//
#include <hip/hip_runtime.h>
#include <hip/hip_bf16.h>
#include <stdint.h>

#define T_TOK 4096
#define H_DIM 1024
#define I_DIM 2816
#define E_NUM 8
#define BK 64

typedef float f32x4 __attribute__((ext_vector_type(4)));
typedef __bf16 bf16x8 __attribute__((ext_vector_type(8)));
typedef __bf16 bf16x4 __attribute__((ext_vector_type(4)));

__device__ __forceinline__ void gload_lds16(const void* g, void* l) {
    __builtin_amdgcn_global_load_lds((const __attribute__((address_space(1))) void*)g,
                                     (__attribute__((address_space(3))) void*)l, 16, 0, 0);
}

__device__ __forceinline__ bf16x8 cvt8(float4 a, float4 b) {
    bf16x8 r;
    r[0] = (__bf16)a.x; r[1] = (__bf16)a.y; r[2] = (__bf16)a.z; r[3] = (__bf16)a.w;
    r[4] = (__bf16)b.x; r[5] = (__bf16)b.y; r[6] = (__bf16)b.z; r[7] = (__bf16)b.w;
    return r;
}

// ---------------- generic f32 -> bf16 (grid-stride over float4) ----------------
__global__ __launch_bounds__(256) void k_cvt(const float* __restrict__ src,
                                             __bf16* __restrict__ dst, int n4) {
    int stride = gridDim.x * 256;
    for (int i = blockIdx.x * 256 + threadIdx.x; i < n4; i += stride) {
        float4 v = ((const float4*)src)[i];
        bf16x4 o;
        o[0] = (__bf16)v.x; o[1] = (__bf16)v.y; o[2] = (__bf16)v.z; o[3] = (__bf16)v.w;
        ((bf16x4*)dst)[i] = o;
    }
}

// ---------------- router ----------------
__global__ __launch_bounds__(256) void k_router(const float* __restrict__ x,
                                                const float* __restrict__ rw,
                                                int* __restrict__ list,
                                                float* __restrict__ wslot,
                                                int* __restrict__ counts) {
    int tid = threadIdx.x;
    int wid = tid >> 6, lane = tid & 63;
    int t = blockIdx.x * 4 + wid;

    float acc[E_NUM];
#pragma unroll
    for (int e = 0; e < E_NUM; ++e) acc[e] = 0.f;

    const float4* x4 = (const float4*)(x + (size_t)t * H_DIM);
    const float4* r4 = (const float4*)rw;
#pragma unroll
    for (int j = 0; j < 4; ++j) {
        float4 xv = x4[j * 64 + lane];
#pragma unroll
        for (int e = 0; e < E_NUM; ++e) {
            float4 wv = r4[e * 256 + j * 64 + lane];
            acc[e] += xv.x * wv.x + xv.y * wv.y + xv.z * wv.z + xv.w * wv.w;
        }
    }
#pragma unroll
    for (int s = 1; s < 64; s <<= 1) {
#pragma unroll
        for (int e = 0; e < E_NUM; ++e) acc[e] += __shfl_xor(acc[e], s, 64);
    }
    if (lane == 0) {
        float best = -1e30f; int be = 0;
#pragma unroll
        for (int e = 0; e < E_NUM; ++e) if (acc[e] > best) { best = acc[e]; be = e; }
        float sec = -1e30f; int se = 0;
#pragma unroll
        for (int e = 0; e < E_NUM; ++e) if (e != be && acc[e] > sec) { sec = acc[e]; se = e; }
        float d = __expf(sec - best);
        float w1 = 1.f / (1.f + d);
        float w2 = d / (1.f + d);
        int p1 = atomicAdd(&counts[be], 1);
        list[be * T_TOK + p1] = 2 * t;
        wslot[2 * t] = w1;
        int p2 = atomicAdd(&counts[se], 1);
        list[se * T_TOK + p2] = 2 * t + 1;
        wslot[2 * t + 1] = w2;
    }
}

// ================= bf16-weight fast path =================

// GEMM1: tile 128(M)x64(N), BK=64, 8 waves (wave 32x32 dual g/u), pure gload_lds pipeline
__global__ __launch_bounds__(512, 4) void k_gemm1_bf(const __bf16* __restrict__ xbf,
                                                     const __bf16* __restrict__ wg,
                                                     const __bf16* __restrict__ wu,
                                                     const int* __restrict__ list,
                                                     const int* __restrict__ counts,
                                                     __bf16* __restrict__ hbuf) {
    __shared__ __attribute__((aligned(16))) unsigned char lA[2][128 * 128];
    __shared__ __attribute__((aligned(16))) unsigned char lBg[2][64 * 128];
    __shared__ __attribute__((aligned(16))) unsigned char lBu[2][64 * 128];
    __shared__ int slots[128];

    const int lid = blockIdx.x;
    const int e = lid & 7;
    const int seq = lid >> 3;
    const int tn = seq >> 5;        // 44
    const int tm = seq & 31;
    const int cnt = counts[e];
    if (tm * 128 >= cnt) return;
    const int tid = threadIdx.x;
    const int lane = tid & 63;
    const int wid = tid >> 6;
    const int wm = wid >> 1;
    const int wn = wid & 1;

    if (tid < 128) {
        int p = tm * 128 + tid;
        slots[tid] = list[e * T_TOK + (p < cnt ? p : cnt - 1)];
    }
    __syncthreads();

    // A staging (gathered rows): 2 gloads/thread
    const char* aSrc[2];
    uint32_t aOff[2];
    {
        int colb = (tid & 7) * 16;
#pragma unroll
        for (int r = 0; r < 2; ++r) {
            int row = r * 64 + (tid >> 3);
            int tok = slots[row] >> 1;
            aSrc[r] = (const char*)xbf + (size_t)tok * (H_DIM * 2) + (colb ^ ((row & 7) << 4));
            aOff[r] = (uint32_t)(row * 128 + colb);
        }
    }
    // B staging: 1 gload/thread per matrix (64 rows x 128B)
    const char* bgSrc;
    const char* buSrc;
    uint32_t bOff;
    {
        int row = tid >> 3;
        int colb = (tid & 7) * 16;
        size_t gr = ((size_t)e * I_DIM + (size_t)tn * 64 + row) * (H_DIM * 2);
        bgSrc = (const char*)wg + gr + (colb ^ ((row & 7) << 4));
        buSrc = (const char*)wu + gr + (colb ^ ((row & 7) << 4));
        bOff = (uint32_t)(row * 128 + colb);
    }

    const f32x4 zero = {0.f, 0.f, 0.f, 0.f};
    f32x4 accg[2][2], accu[2][2];
#pragma unroll
    for (int i = 0; i < 2; ++i)
#pragma unroll
        for (int j = 0; j < 2; ++j) { accg[i][j] = zero; accu[i][j] = zero; }

    // prologue: stage kt=0 (4 gloads in flight)
    gload_lds16(aSrc[0], &lA[0][aOff[0]]);
    gload_lds16(aSrc[1], &lA[0][aOff[1]]);
    gload_lds16(bgSrc, &lBg[0][bOff]);
    gload_lds16(buSrc, &lBu[0][bOff]);

    const int NT = H_DIM / BK;
    for (int kt = 0; kt < NT; ++kt) {
        const int cur = kt & 1, nxt = cur ^ 1;
        const bool pf = (kt + 1 < NT);
        if (pf) {
            gload_lds16(aSrc[0] + (kt + 1) * 128, &lA[nxt][aOff[0]]);
            gload_lds16(aSrc[1] + (kt + 1) * 128, &lA[nxt][aOff[1]]);
            gload_lds16(bgSrc + (kt + 1) * 128, &lBg[nxt][bOff]);
            gload_lds16(buSrc + (kt + 1) * 128, &lBu[nxt][bOff]);
        }
        __builtin_amdgcn_sched_barrier(0);
        if (pf) { asm volatile("s_waitcnt vmcnt(4)" ::: "memory"); }
        else    { asm volatile("s_waitcnt vmcnt(0)" ::: "memory"); }
        __builtin_amdgcn_sched_barrier(0);
        __builtin_amdgcn_s_barrier();
        __builtin_amdgcn_sched_barrier(0);
#pragma unroll
        for (int kk = 0; kk < 2; ++kk) {
            bf16x8 av[2], bg[2], bu[2];
#pragma unroll
            for (int mi = 0; mi < 2; ++mi) {
                int row = wm * 32 + mi * 16 + (lane & 15);
                int byte = (row * 128 + kk * 64 + (lane >> 4) * 16) ^ ((row & 7) << 4);
                av[mi] = *(const bf16x8*)&lA[cur][byte];
            }
#pragma unroll
            for (int ni = 0; ni < 2; ++ni) {
                int row = wn * 32 + ni * 16 + (lane & 15);
                int byte = (row * 128 + kk * 64 + (lane >> 4) * 16) ^ ((row & 7) << 4);
                bg[ni] = *(const bf16x8*)&lBg[cur][byte];
                bu[ni] = *(const bf16x8*)&lBu[cur][byte];
            }
#pragma unroll
            for (int mi = 0; mi < 2; ++mi)
#pragma unroll
                for (int ni = 0; ni < 2; ++ni) {
                    accg[mi][ni] = __builtin_amdgcn_mfma_f32_16x16x32_bf16(av[mi], bg[ni], accg[mi][ni], 0, 0, 0);
                    accu[mi][ni] = __builtin_amdgcn_mfma_f32_16x16x32_bf16(av[mi], bu[ni], accu[mi][ni], 0, 0, 0);
                }
        }
        __builtin_amdgcn_sched_barrier(0);
        __builtin_amdgcn_s_barrier();   // WAR: next iter's gloads overwrite lA/lB[cur]
        __builtin_amdgcn_sched_barrier(0);
    }

#pragma unroll
    for (int mi = 0; mi < 2; ++mi) {
#pragma unroll
        for (int ni = 0; ni < 2; ++ni) {
            int col = tn * 64 + wn * 32 + ni * 16 + (lane & 15);
#pragma unroll
            for (int r = 0; r < 4; ++r) {
                int trow = wm * 32 + mi * 16 + ((lane >> 4) << 2) + r;
                if (tm * 128 + trow < cnt) {
                    float g = accg[mi][ni][r];
                    float u = accu[mi][ni][r];
                    float hv = (g / (1.f + __expf(-g))) * u;
                    hbuf[(size_t)slots[trow] * I_DIM + col] = (__bf16)hv;
                }
            }
        }
    }
}

// GEMM2: tile 128(M)x128(N), BK=64, 8 waves (wave 32x64), pure gload_lds pipeline
__global__ __launch_bounds__(512, 4) void k_gemm2_bf(const __bf16* __restrict__ hbuf,
                                                     const __bf16* __restrict__ wd,
                                                     const int* __restrict__ list,
                                                     const int* __restrict__ counts,
                                                     const float* __restrict__ wslot,
                                                     float* __restrict__ out) {
    __shared__ __attribute__((aligned(16))) unsigned char lA[2][128 * 128];
    __shared__ __attribute__((aligned(16))) unsigned char lB[2][128 * 128];
    __shared__ int slots[128];
    __shared__ float wr[128];

    const int lid = blockIdx.x;
    const int e = lid & 7;
    const int s = lid >> 3;             // 0..255
    const int tm2 = s & 1;
    const int tn = (s >> 1) & 7;        // tn-inner per tm-pair: A stays L2-resident
    const int tm = (s >> 4) * 2 + tm2;
    const int cnt = counts[e];
    if (tm * 128 >= cnt) return;
    const int tid = threadIdx.x;
    const int lane = tid & 63;
    const int wid = tid >> 6;
    const int wm = wid >> 1;
    const int wn = wid & 1;

    if (tid < 128) {
        int p = tm * 128 + tid;
        int sl = list[e * T_TOK + (p < cnt ? p : cnt - 1)];
        slots[tid] = sl;
        wr[tid] = wslot[sl];
    }
    __syncthreads();

    const char* aSrc[2];
    uint32_t aOff[2];
    {
        int colb = (tid & 7) * 16;
#pragma unroll
        for (int r = 0; r < 2; ++r) {
            int row = r * 64 + (tid >> 3);
            aSrc[r] = (const char*)hbuf + (size_t)slots[row] * (I_DIM * 2) + (colb ^ ((row & 7) << 4));
            aOff[r] = (uint32_t)(row * 128 + colb);
        }
    }
    const char* bSrc[2];
    uint32_t bOff[2];
    {
        int colb = (tid & 7) * 16;
#pragma unroll
        for (int r = 0; r < 2; ++r) {
            int row = r * 64 + (tid >> 3);
            bSrc[r] = (const char*)wd + ((size_t)e * H_DIM + (size_t)tn * 128 + row) * (I_DIM * 2)
                      + (colb ^ ((row & 7) << 4));
            bOff[r] = (uint32_t)(row * 128 + colb);
        }
    }

    const f32x4 zero = {0.f, 0.f, 0.f, 0.f};
    f32x4 acc[2][4];
#pragma unroll
    for (int i = 0; i < 2; ++i)
#pragma unroll
        for (int j = 0; j < 4; ++j) acc[i][j] = zero;

    gload_lds16(aSrc[0], &lA[0][aOff[0]]);
    gload_lds16(aSrc[1], &lA[0][aOff[1]]);
    gload_lds16(bSrc[0], &lB[0][bOff[0]]);
    gload_lds16(bSrc[1], &lB[0][bOff[1]]);

    const int NT = I_DIM / BK;
    for (int kt = 0; kt < NT; ++kt) {
        const int cur = kt & 1, nxt = cur ^ 1;
        const bool pf = (kt + 1 < NT);
        if (pf) {
            gload_lds16(aSrc[0] + (kt + 1) * 128, &lA[nxt][aOff[0]]);
            gload_lds16(aSrc[1] + (kt + 1) * 128, &lA[nxt][aOff[1]]);
            gload_lds16(bSrc[0] + (kt + 1) * 128, &lB[nxt][bOff[0]]);
            gload_lds16(bSrc[1] + (kt + 1) * 128, &lB[nxt][bOff[1]]);
        }
        __builtin_amdgcn_sched_barrier(0);
        if (pf) { asm volatile("s_waitcnt vmcnt(4)" ::: "memory"); }
        else    { asm volatile("s_waitcnt vmcnt(0)" ::: "memory"); }
        __builtin_amdgcn_sched_barrier(0);
        __builtin_amdgcn_s_barrier();
        __builtin_amdgcn_sched_barrier(0);
#pragma unroll
        for (int kk = 0; kk < 2; ++kk) {
            bf16x8 av[2], bv[4];
#pragma unroll
            for (int mi = 0; mi < 2; ++mi) {
                int row = wm * 32 + mi * 16 + (lane & 15);
                int byte = (row * 128 + kk * 64 + (lane >> 4) * 16) ^ ((row & 7) << 4);
                av[mi] = *(const bf16x8*)&lA[cur][byte];
            }
#pragma unroll
            for (int ni = 0; ni < 4; ++ni) {
                int row = wn * 64 + ni * 16 + (lane & 15);
                int byte = (row * 128 + kk * 64 + (lane >> 4) * 16) ^ ((row & 7) << 4);
                bv[ni] = *(const bf16x8*)&lB[cur][byte];
            }
#pragma unroll
            for (int mi = 0; mi < 2; ++mi)
#pragma unroll
                for (int ni = 0; ni < 4; ++ni)
                    acc[mi][ni] = __builtin_amdgcn_mfma_f32_16x16x32_bf16(av[mi], bv[ni], acc[mi][ni], 0, 0, 0);
        }
        __builtin_amdgcn_sched_barrier(0);
        __builtin_amdgcn_s_barrier();
        __builtin_amdgcn_sched_barrier(0);
    }

#pragma unroll
    for (int mi = 0; mi < 2; ++mi) {
#pragma unroll
        for (int ni = 0; ni < 4; ++ni) {
            int col = tn * 128 + wn * 64 + ni * 16 + (lane & 15);
#pragma unroll
            for (int r = 0; r < 4; ++r) {
                int trow = wm * 32 + mi * 16 + ((lane >> 4) << 2) + r;
                if (tm * 128 + trow < cnt) {
                    int t = slots[trow] >> 1;
                    atomicAdd(out + (size_t)t * H_DIM + col, acc[mi][ni][r] * wr[trow]);
                }
            }
        }
    }
}

// ================= f32-weight fallback (round-3 proven path) =================

__global__ __launch_bounds__(512, 4) void k_gemm1_f32(const __bf16* __restrict__ xbf,
                                                      const float* __restrict__ Wg,
                                                      const float* __restrict__ Wu,
                                                      const int* __restrict__ list,
                                                      const int* __restrict__ counts,
                                                      __bf16* __restrict__ hbuf) {
    __shared__ __attribute__((aligned(16))) unsigned char lA[2][128 * BK * 2];
    __shared__ __attribute__((aligned(16))) unsigned char lBg[2][64 * BK * 2];
    __shared__ __attribute__((aligned(16))) unsigned char lBu[2][64 * BK * 2];
    __shared__ int slots[128];

    const int lid = blockIdx.x;
    const int e = lid & 7;
    const int seq = lid >> 3;
    const int tn = seq >> 5;
    const int tm = seq & 31;
    const int cnt = counts[e];
    if (tm * 128 >= cnt) return;
    const int tid = threadIdx.x;
    const int lane = tid & 63;
    const int wid = tid >> 6;
    const int wm = wid >> 1;
    const int wn = wid & 1;

    if (tid < 128) {
        int p = tm * 128 + tid;
        slots[tid] = list[e * T_TOK + (p < cnt ? p : cnt - 1)];
    }
    __syncthreads();

    const char* aSrc[2];
    uint32_t aOff[2];
    {
        int colb = (tid & 7) * 16;
#pragma unroll
        for (int r = 0; r < 2; ++r) {
            int row = r * 64 + (tid >> 3);
            int tok = slots[row] >> 1;
            aSrc[r] = (const char*)xbf + (size_t)tok * (H_DIM * 2) + (colb ^ ((row & 7) << 4));
            aOff[r] = (uint32_t)(row * 128 + colb);
        }
    }
    const int brow = tid >> 3;
    const int bq = tid & 7;
    const float* srcg = Wg + ((size_t)e * I_DIM + (size_t)tn * 64 + brow) * H_DIM + bq * 8;
    const float* srcu = Wu + ((size_t)e * I_DIM + (size_t)tn * 64 + brow) * H_DIM + bq * 8;
    const uint32_t bOff = (uint32_t)((brow * 128 + bq * 16) ^ ((brow & 7) << 4));

    const f32x4 zero = {0.f, 0.f, 0.f, 0.f};
    f32x4 accg[2][2], accu[2][2];
#pragma unroll
    for (int i = 0; i < 2; ++i)
#pragma unroll
        for (int j = 0; j < 2; ++j) { accg[i][j] = zero; accu[i][j] = zero; }

    gload_lds16(aSrc[0], &lA[0][aOff[0]]);
    gload_lds16(aSrc[1], &lA[0][aOff[1]]);
    float4 g0 = ((const float4*)srcg)[0], g1 = ((const float4*)srcg)[1];
    float4 u0 = ((const float4*)srcu)[0], u1 = ((const float4*)srcu)[1];

    const int NT = H_DIM / BK;
    for (int kt = 0; kt < NT; ++kt) {
        const int cur = kt & 1, nxt = cur ^ 1;
        float4 ng0, ng1, nu0, nu1;
        const bool pf = (kt + 1 < NT);
        if (pf) {
            gload_lds16(aSrc[0] + (kt + 1) * 128, &lA[nxt][aOff[0]]);
            gload_lds16(aSrc[1] + (kt + 1) * 128, &lA[nxt][aOff[1]]);
            const float4* pg = (const float4*)(srcg + (kt + 1) * BK);
            const float4* pu = (const float4*)(srcu + (kt + 1) * BK);
            ng0 = pg[0]; ng1 = pg[1]; nu0 = pu[0]; nu1 = pu[1];
        }
        __builtin_amdgcn_sched_barrier(0);
        if (pf) { asm volatile("s_waitcnt vmcnt(6)" ::: "memory"); }
        else    { asm volatile("s_waitcnt vmcnt(0)" ::: "memory"); }
        __builtin_amdgcn_sched_barrier(0);
        *(bf16x8*)&lBg[cur][bOff] = cvt8(g0, g1);
        *(bf16x8*)&lBu[cur][bOff] = cvt8(u0, u1);
        asm volatile("s_waitcnt lgkmcnt(0)" ::: "memory");
        __builtin_amdgcn_sched_barrier(0);
        __builtin_amdgcn_s_barrier();
        __builtin_amdgcn_sched_barrier(0);
#pragma unroll
        for (int kk = 0; kk < 2; ++kk) {
            bf16x8 av[2], bg[2], bu[2];
#pragma unroll
            for (int mi = 0; mi < 2; ++mi) {
                int row = wm * 32 + mi * 16 + (lane & 15);
                int byte = (row * 128 + kk * 64 + (lane >> 4) * 16) ^ ((row & 7) << 4);
                av[mi] = *(const bf16x8*)&lA[cur][byte];
            }
#pragma unroll
            for (int ni = 0; ni < 2; ++ni) {
                int row = wn * 32 + ni * 16 + (lane & 15);
                int byte = (row * 128 + kk * 64 + (lane >> 4) * 16) ^ ((row & 7) << 4);
                bg[ni] = *(const bf16x8*)&lBg[cur][byte];
                bu[ni] = *(const bf16x8*)&lBu[cur][byte];
            }
#pragma unroll
            for (int mi = 0; mi < 2; ++mi)
#pragma unroll
                for (int ni = 0; ni < 2; ++ni) {
                    accg[mi][ni] = __builtin_amdgcn_mfma_f32_16x16x32_bf16(av[mi], bg[ni], accg[mi][ni], 0, 0, 0);
                    accu[mi][ni] = __builtin_amdgcn_mfma_f32_16x16x32_bf16(av[mi], bu[ni], accu[mi][ni], 0, 0, 0);
                }
        }
        __builtin_amdgcn_sched_barrier(0);
        __builtin_amdgcn_s_barrier();
        __builtin_amdgcn_sched_barrier(0);
        if (pf) { g0 = ng0; g1 = ng1; u0 = nu0; u1 = nu1; }
    }

#pragma unroll
    for (int mi = 0; mi < 2; ++mi) {
#pragma unroll
        for (int ni = 0; ni < 2; ++ni) {
            int col = tn * 64 + wn * 32 + ni * 16 + (lane & 15);
#pragma unroll
            for (int r = 0; r < 4; ++r) {
                int trow = wm * 32 + mi * 16 + ((lane >> 4) << 2) + r;
                if (tm * 128 + trow < cnt) {
                    float g = accg[mi][ni][r];
                    float u = accu[mi][ni][r];
                    float hv = (g / (1.f + __expf(-g))) * u;
                    hbuf[(size_t)slots[trow] * I_DIM + col] = (__bf16)hv;
                }
            }
        }
    }
}

__global__ __launch_bounds__(512, 4) void k_gemm2_f32(const __bf16* __restrict__ hbuf,
                                                      const float* __restrict__ Wd,
                                                      const int* __restrict__ list,
                                                      const int* __restrict__ counts,
                                                      const float* __restrict__ wslot,
                                                      float* __restrict__ out) {
    __shared__ __attribute__((aligned(16))) unsigned char lA[2][128 * BK * 2];
    __shared__ __attribute__((aligned(16))) unsigned char lB[2][128 * BK * 2];
    __shared__ int slots[128];
    __shared__ float wr[128];

    const int lid = blockIdx.x;
    const int e = lid & 7;
    const int seq = lid >> 3;
    const int tn = seq >> 5;
    const int tm = seq & 31;
    const int cnt = counts[e];
    if (tm * 128 >= cnt) return;
    const int tid = threadIdx.x;
    const int lane = tid & 63;
    const int wid = tid >> 6;
    const int wm = wid >> 1;
    const int wn = wid & 1;

    if (tid < 128) {
        int p = tm * 128 + tid;
        int sl = list[e * T_TOK + (p < cnt ? p : cnt - 1)];
        slots[tid] = sl;
        wr[tid] = wslot[sl];
    }
    __syncthreads();

    const char* aSrc[2];
    uint32_t aOff[2];
    {
        int colb = (tid & 7) * 16;
#pragma unroll
        for (int r = 0; r < 2; ++r) {
            int row = r * 64 + (tid >> 3);
            aSrc[r] = (const char*)hbuf + (size_t)slots[row] * (I_DIM * 2) + (colb ^ ((row & 7) << 4));
            aOff[r] = (uint32_t)(row * 128 + colb);
        }
    }
    const int brow = tid >> 2;
    const int bq = tid & 3;
    const float* srcb = Wd + ((size_t)e * H_DIM + (size_t)tn * 128 + brow) * I_DIM + bq * 16;
    const uint32_t bOff0 = (uint32_t)((brow * 128 + bq * 32) ^ ((brow & 7) << 4));
    const uint32_t bOff1 = (uint32_t)((brow * 128 + bq * 32 + 16) ^ ((brow & 7) << 4));

    const f32x4 zero = {0.f, 0.f, 0.f, 0.f};
    f32x4 acc[2][4];
#pragma unroll
    for (int i = 0; i < 2; ++i)
#pragma unroll
        for (int j = 0; j < 4; ++j) acc[i][j] = zero;

    gload_lds16(aSrc[0], &lA[0][aOff[0]]);
    gload_lds16(aSrc[1], &lA[0][aOff[1]]);
    float4 w0 = ((const float4*)srcb)[0], w1 = ((const float4*)srcb)[1];
    float4 w2 = ((const float4*)srcb)[2], w3 = ((const float4*)srcb)[3];

    const int NT = I_DIM / BK;
    for (int kt = 0; kt < NT; ++kt) {
        const int cur = kt & 1, nxt = cur ^ 1;
        float4 nw0, nw1, nw2, nw3;
        const bool pf = (kt + 1 < NT);
        if (pf) {
            gload_lds16(aSrc[0] + (kt + 1) * 128, &lA[nxt][aOff[0]]);
            gload_lds16(aSrc[1] + (kt + 1) * 128, &lA[nxt][aOff[1]]);
            const float4* pb = (const float4*)(srcb + (kt + 1) * BK);
            nw0 = pb[0]; nw1 = pb[1]; nw2 = pb[2]; nw3 = pb[3];
        }
        __builtin_amdgcn_sched_barrier(0);
        if (pf) { asm volatile("s_waitcnt vmcnt(6)" ::: "memory"); }
        else    { asm volatile("s_waitcnt vmcnt(0)" ::: "memory"); }
        __builtin_amdgcn_sched_barrier(0);
        *(bf16x8*)&lB[cur][bOff0] = cvt8(w0, w1);
        *(bf16x8*)&lB[cur][bOff1] = cvt8(w2, w3);
        asm volatile("s_waitcnt lgkmcnt(0)" ::: "memory");
        __builtin_amdgcn_sched_barrier(0);
        __builtin_amdgcn_s_barrier();
        __builtin_amdgcn_sched_barrier(0);
#pragma unroll
        for (int kk = 0; kk < 2; ++kk) {
            bf16x8 av[2], bv[4];
#pragma unroll
            for (int mi = 0; mi < 2; ++mi) {
                int row = wm * 32 + mi * 16 + (lane & 15);
                int byte = (row * 128 + kk * 64 + (lane >> 4) * 16) ^ ((row & 7) << 4);
                av[mi] = *(const bf16x8*)&lA[cur][byte];
            }
#pragma unroll
            for (int ni = 0; ni < 4; ++ni) {
                int row = wn * 64 + ni * 16 + (lane & 15);
                int byte = (row * 128 + kk * 64 + (lane >> 4) * 16) ^ ((row & 7) << 4);
                bv[ni] = *(const bf16x8*)&lB[cur][byte];
            }
#pragma unroll
            for (int mi = 0; mi < 2; ++mi)
#pragma unroll
                for (int ni = 0; ni < 4; ++ni)
                    acc[mi][ni] = __builtin_amdgcn_mfma_f32_16x16x32_bf16(av[mi], bv[ni], acc[mi][ni], 0, 0, 0);
        }
        __builtin_amdgcn_sched_barrier(0);
        __builtin_amdgcn_s_barrier();
        __builtin_amdgcn_sched_barrier(0);
        if (pf) { w0 = nw0; w1 = nw1; w2 = nw2; w3 = nw3; }
    }

#pragma unroll
    for (int mi = 0; mi < 2; ++mi) {
#pragma unroll
        for (int ni = 0; ni < 4; ++ni) {
            int col = tn * 128 + wn * 64 + ni * 16 + (lane & 15);
#pragma unroll
            for (int r = 0; r < 4; ++r) {
                int trow = wm * 32 + mi * 16 + ((lane >> 4) << 2) + r;
                if (tm * 128 + trow < cnt) {
                    int t = slots[trow] >> 1;
                    atomicAdd(out + (size_t)t * H_DIM + col, acc[mi][ni][r] * wr[trow]);
                }
            }
        }
    }
}

extern "C" void kernel_launch(void* const* d_in, const int* in_sizes, int n_in,
                              void* d_out, int out_size, void* d_ws, size_t ws_size,
                              hipStream_t stream) {
    const float* x  = (const float*)d_in[0];
    const float* rw = (const float*)d_in[1];
    const float* Wg = (const float*)d_in[2];
    const float* Wu = (const float*)d_in[3];
    const float* Wd = (const float*)d_in[4];
    float* out = (float*)d_out;

    char* ws = (char*)d_ws;
    const size_t SZ_X   = 8388608;     // xbf
    const size_t SZ_W   = 46137344;    // each bf16 weight tensor
    const size_t NEED   = SZ_X + 4 * SZ_W + 131072 + 32768 + 32;  // 193,101,856

    hipMemsetAsync(d_out, 0, (size_t)out_size * sizeof(float), stream);

    if (ws_size >= NEED) {
        __bf16* xbf   = (__bf16*)(ws);
        __bf16* wg_bf = (__bf16*)(ws + SZ_X);
        __bf16* wu_bf = (__bf16*)(ws + SZ_X + SZ_W);
        __bf16* wd_bf = (__bf16*)(ws + SZ_X + 2 * SZ_W);
        __bf16* hbuf  = (__bf16*)(ws + SZ_X + 3 * SZ_W);
        int*    list  = (int*)(ws + SZ_X + 4 * SZ_W);
        float*  wslot = (float*)(ws + SZ_X + 4 * SZ_W + 131072);
        int*    counts= (int*)(ws + SZ_X + 4 * SZ_W + 131072 + 32768);

        hipMemsetAsync(counts, 0, E_NUM * sizeof(int), stream);
        k_cvt<<<1024, 256, 0, stream>>>(x,  xbf,   (T_TOK * H_DIM) / 4);
        k_cvt<<<2048, 256, 0, stream>>>(Wg, wg_bf, (E_NUM * I_DIM * H_DIM) / 4);
        k_cvt<<<2048, 256, 0, stream>>>(Wu, wu_bf, (E_NUM * I_DIM * H_DIM) / 4);
        k_cvt<<<2048, 256, 0, stream>>>(Wd, wd_bf, (E_NUM * I_DIM * H_DIM) / 4);
        k_router<<<T_TOK / 4, 256, 0, stream>>>(x, rw, list, wslot, counts);
        k_gemm1_bf<<<8 * 44 * 32, 512, 0, stream>>>(xbf, wg_bf, wu_bf, list, counts, hbuf);
        k_gemm2_bf<<<8 * 8 * 32, 512, 0, stream>>>(hbuf, wd_bf, list, counts, wslot, out);
    } else {
        __bf16* xbf   = (__bf16*)(ws);
        __bf16* hbuf  = (__bf16*)(ws + 8388608);
        int*    list  = (int*)(ws + 54525952);
        float*  wslot = (float*)(ws + 54657024);
        int*    counts= (int*)(ws + 54689792);

        hipMemsetAsync(counts, 0, E_NUM * sizeof(int), stream);
        k_cvt<<<1024, 256, 0, stream>>>(x, xbf, (T_TOK * H_DIM) / 4);
        k_router<<<T_TOK / 4, 256, 0, stream>>>(x, rw, list, wslot, counts);
        k_gemm1_f32<<<8 * 44 * 32, 512, 0, stream>>>(xbf, Wg, Wu, list, counts, hbuf);
        k_gemm2_f32<<<8 * 8 * 32, 512, 0, stream>>>(hbuf, Wd, list, counts, wslot, out);
    }
}

// Round 5
// 454.595 us; speedup vs baseline: 4.4148x; 1.0136x over previous
//
#include <hip/hip_runtime.h>
#include <hip/hip_bf16.h>
#include <stdint.h>

#define T_TOK 4096
#define H_DIM 1024
#define I_DIM 2816
#define E_NUM 8
#define BK 64
#define NW4 5767168           // float4 count per weight tensor (8*2816*1024/4)
#define W_ELEMS 23068672      // elements per weight tensor

typedef float f32x4 __attribute__((ext_vector_type(4)));
typedef __bf16 bf16x8 __attribute__((ext_vector_type(8)));
typedef __bf16 bf16x4 __attribute__((ext_vector_type(4)));

__device__ __forceinline__ void gload_lds16(const void* g, void* l) {
    __builtin_amdgcn_global_load_lds((const __attribute__((address_space(1))) void*)g,
                                     (__attribute__((address_space(3))) void*)l, 16, 0, 0);
}

__device__ __forceinline__ bf16x4 cvt4(float4 v) {
    bf16x4 o;
    o[0] = (__bf16)v.x; o[1] = (__bf16)v.y; o[2] = (__bf16)v.z; o[3] = (__bf16)v.w;
    return o;
}

// ---------- fused: weight cvt (blocks 0..2047) + router & x-cvt (blocks 2048..3071) ----------
__global__ __launch_bounds__(256) void k_router_cvt(const float* __restrict__ x,
                                                    const float* __restrict__ rw,
                                                    const float* __restrict__ Wg,
                                                    const float* __restrict__ Wu,
                                                    const float* __restrict__ Wd,
                                                    __bf16* __restrict__ xbf,
                                                    __bf16* __restrict__ wbf,
                                                    int* __restrict__ list,
                                                    float* __restrict__ wslot,
                                                    int* __restrict__ counts) {
    const int b = blockIdx.x;
    if (b < 2048) {
        // convert Wg | Wu | Wd -> contiguous bf16 region wbf
        const int stride = 2048 * 256;
        for (int i = b * 256 + threadIdx.x; i < 3 * NW4; i += stride) {
            float4 v;
            if (i < NW4)            v = ((const float4*)Wg)[i];
            else if (i < 2 * NW4)   v = ((const float4*)Wu)[i - NW4];
            else                    v = ((const float4*)Wd)[i - 2 * NW4];
            ((bf16x4*)wbf)[i] = cvt4(v);
        }
        return;
    }
    // router: 4 tokens per block (1 per wave), also emits xbf
    const int rb = b - 2048;
    const int tid = threadIdx.x;
    const int wid = tid >> 6, lane = tid & 63;
    const int t = rb * 4 + wid;

    float acc[E_NUM];
#pragma unroll
    for (int e = 0; e < E_NUM; ++e) acc[e] = 0.f;

    const float4* x4 = (const float4*)(x + (size_t)t * H_DIM);
    const float4* r4 = (const float4*)rw;
#pragma unroll
    for (int j = 0; j < 4; ++j) {
        float4 xv = x4[j * 64 + lane];
        ((bf16x4*)xbf)[(size_t)t * 256 + j * 64 + lane] = cvt4(xv);
#pragma unroll
        for (int e = 0; e < E_NUM; ++e) {
            float4 wv = r4[e * 256 + j * 64 + lane];
            acc[e] += xv.x * wv.x + xv.y * wv.y + xv.z * wv.z + xv.w * wv.w;
        }
    }
#pragma unroll
    for (int s = 1; s < 64; s <<= 1) {
#pragma unroll
        for (int e = 0; e < E_NUM; ++e) acc[e] += __shfl_xor(acc[e], s, 64);
    }
    if (lane == 0) {
        float best = -1e30f; int be = 0;
#pragma unroll
        for (int e = 0; e < E_NUM; ++e) if (acc[e] > best) { best = acc[e]; be = e; }
        float sec = -1e30f; int se = 0;
#pragma unroll
        for (int e = 0; e < E_NUM; ++e) if (e != be && acc[e] > sec) { sec = acc[e]; se = e; }
        float d = __expf(sec - best);
        float w1 = 1.f / (1.f + d);
        float w2 = d / (1.f + d);
        int p1 = atomicAdd(&counts[be], 1);
        list[be * T_TOK + p1] = 2 * t;
        wslot[2 * t] = w1;
        int p2 = atomicAdd(&counts[se], 1);
        list[se * T_TOK + p2] = 2 * t + 1;
        wslot[2 * t + 1] = w2;
    }
}

// ---------- GEMM1: tile 128(M)x64(N), BK=64, 256 thr / 4 waves, wave 64x32 dual g/u ----------
__global__ __launch_bounds__(256, 2) void k_gemm1(const __bf16* __restrict__ xbf,
                                                  const __bf16* __restrict__ wbf,
                                                  const int* __restrict__ list,
                                                  const int* __restrict__ counts,
                                                  __bf16* __restrict__ hbuf) {
    __shared__ __attribute__((aligned(16))) unsigned char lA[2][128 * 128];
    __shared__ __attribute__((aligned(16))) unsigned char lBg[2][64 * 128];
    __shared__ __attribute__((aligned(16))) unsigned char lBu[2][64 * 128];
    __shared__ int slots[128];

    const __bf16* wg = wbf;
    const __bf16* wu = wbf + (size_t)W_ELEMS;

    const int lid = blockIdx.x;
    const int e = lid & 7;          // expert pinned to XCD
    const int seq = lid >> 3;
    const int tn = seq >> 5;        // 44 tiles of 64 cols
    const int tm = seq & 31;        // tm inner: B panel reused by consecutive blocks
    const int cnt = counts[e];
    if (tm * 128 >= cnt) return;
    const int tid = threadIdx.x;
    const int lane = tid & 63;
    const int wid = tid >> 6;
    const int wm = wid >> 1;        // 2 x 64 rows
    const int wn = wid & 1;         // 2 x 32 cols

    if (tid < 128) {
        int p = tm * 128 + tid;
        slots[tid] = list[e * T_TOK + (p < cnt ? p : cnt - 1)];
    }
    __syncthreads();   // also drains vmcnt to 0 baseline

    // A staging: 128 rows x 128B, 4 gloads/thread (source pre-swizzled)
    const char* aSrc[4];
    uint32_t aOff[4];
    {
        int colb = (tid & 7) * 16;
#pragma unroll
        for (int r = 0; r < 4; ++r) {
            int row = r * 32 + (tid >> 3);
            int tok = slots[row] >> 1;
            aSrc[r] = (const char*)xbf + (size_t)tok * (H_DIM * 2) + (colb ^ ((row & 7) << 4));
            aOff[r] = (uint32_t)(row * 128 + colb);
        }
    }
    // B staging: 64 rows x 128B per matrix, 2 gloads/thread each
    const char* bgSrc[2];
    const char* buSrc[2];
    uint32_t bOff[2];
    {
        int colb = (tid & 7) * 16;
#pragma unroll
        for (int r = 0; r < 2; ++r) {
            int row = r * 32 + (tid >> 3);
            size_t gr = ((size_t)e * I_DIM + (size_t)tn * 64 + row) * (H_DIM * 2) + (colb ^ ((row & 7) << 4));
            bgSrc[r] = (const char*)wg + gr;
            buSrc[r] = (const char*)wu + gr;
            bOff[r] = (uint32_t)(row * 128 + colb);
        }
    }

    const f32x4 zero = {0.f, 0.f, 0.f, 0.f};
    f32x4 accg[4][2], accu[4][2];
#pragma unroll
    for (int i = 0; i < 4; ++i)
#pragma unroll
        for (int j = 0; j < 2; ++j) { accg[i][j] = zero; accu[i][j] = zero; }

    // prologue: stage kt=0 (8 gloads in flight)
#pragma unroll
    for (int r = 0; r < 4; ++r) gload_lds16(aSrc[r], &lA[0][aOff[r]]);
#pragma unroll
    for (int r = 0; r < 2; ++r) {
        gload_lds16(bgSrc[r], &lBg[0][bOff[r]]);
        gload_lds16(buSrc[r], &lBu[0][bOff[r]]);
    }

    const int NT = H_DIM / BK;
    for (int kt = 0; kt < NT; ++kt) {
        const int cur = kt & 1, nxt = cur ^ 1;
        const bool pf = (kt + 1 < NT);
        if (pf) {
#pragma unroll
            for (int r = 0; r < 4; ++r) gload_lds16(aSrc[r] + (kt + 1) * 128, &lA[nxt][aOff[r]]);
#pragma unroll
            for (int r = 0; r < 2; ++r) {
                gload_lds16(bgSrc[r] + (kt + 1) * 128, &lBg[nxt][bOff[r]]);
                gload_lds16(buSrc[r] + (kt + 1) * 128, &lBu[nxt][bOff[r]]);
            }
        }
        __builtin_amdgcn_sched_barrier(0);
        if (pf) { asm volatile("s_waitcnt vmcnt(8)" ::: "memory"); }
        else    { asm volatile("s_waitcnt vmcnt(0)" ::: "memory"); }
        __builtin_amdgcn_sched_barrier(0);
        __builtin_amdgcn_s_barrier();
        __builtin_amdgcn_sched_barrier(0);
#pragma unroll
        for (int kk = 0; kk < 2; ++kk) {
            bf16x8 av[4], bg[2], bu[2];
#pragma unroll
            for (int mi = 0; mi < 4; ++mi) {
                int row = wm * 64 + mi * 16 + (lane & 15);
                int byte = (row * 128 + kk * 64 + (lane >> 4) * 16) ^ ((row & 7) << 4);
                av[mi] = *(const bf16x8*)&lA[cur][byte];
            }
#pragma unroll
            for (int ni = 0; ni < 2; ++ni) {
                int row = wn * 32 + ni * 16 + (lane & 15);
                int byte = (row * 128 + kk * 64 + (lane >> 4) * 16) ^ ((row & 7) << 4);
                bg[ni] = *(const bf16x8*)&lBg[cur][byte];
                bu[ni] = *(const bf16x8*)&lBu[cur][byte];
            }
#pragma unroll
            for (int mi = 0; mi < 4; ++mi)
#pragma unroll
                for (int ni = 0; ni < 2; ++ni) {
                    accg[mi][ni] = __builtin_amdgcn_mfma_f32_16x16x32_bf16(av[mi], bg[ni], accg[mi][ni], 0, 0, 0);
                    accu[mi][ni] = __builtin_amdgcn_mfma_f32_16x16x32_bf16(av[mi], bu[ni], accu[mi][ni], 0, 0, 0);
                }
        }
        __builtin_amdgcn_sched_barrier(0);
        __builtin_amdgcn_s_barrier();   // WAR: next iter's gloads overwrite buffers[cur]
        __builtin_amdgcn_sched_barrier(0);
    }

#pragma unroll
    for (int mi = 0; mi < 4; ++mi) {
#pragma unroll
        for (int ni = 0; ni < 2; ++ni) {
            int col = tn * 64 + wn * 32 + ni * 16 + (lane & 15);
#pragma unroll
            for (int r = 0; r < 4; ++r) {
                int trow = wm * 64 + mi * 16 + ((lane >> 4) << 2) + r;
                if (tm * 128 + trow < cnt) {
                    float g = accg[mi][ni][r];
                    float u = accu[mi][ni][r];
                    float hv = (g / (1.f + __expf(-g))) * u;
                    hbuf[(size_t)slots[trow] * I_DIM + col] = (__bf16)hv;
                }
            }
        }
    }
}

// ---------- GEMM2: tile 128(M)x128(N), BK=64, 256 thr / 4 waves, wave 64x64 ----------
__global__ __launch_bounds__(256, 2) void k_gemm2(const __bf16* __restrict__ hbuf,
                                                  const __bf16* __restrict__ wbf,
                                                  const int* __restrict__ list,
                                                  const int* __restrict__ counts,
                                                  const float* __restrict__ wslot,
                                                  float* __restrict__ out) {
    __shared__ __attribute__((aligned(16))) unsigned char lA[2][128 * 128];
    __shared__ __attribute__((aligned(16))) unsigned char lB[2][128 * 128];
    __shared__ int slots[128];
    __shared__ float wr[128];

    const __bf16* wd = wbf + 2 * (size_t)W_ELEMS;

    const int lid = blockIdx.x;
    const int e = lid & 7;
    const int seq = lid >> 3;
    const int tn = seq & 7;         // tn inner: A panel reused across tn sweep
    const int tm = seq >> 3;
    const int cnt = counts[e];
    if (tm * 128 >= cnt) return;
    const int tid = threadIdx.x;
    const int lane = tid & 63;
    const int wid = tid >> 6;
    const int wm = wid >> 1;        // 2 x 64 rows
    const int wn = wid & 1;         // 2 x 64 cols

    if (tid < 128) {
        int p = tm * 128 + tid;
        int sl = list[e * T_TOK + (p < cnt ? p : cnt - 1)];
        slots[tid] = sl;
        wr[tid] = wslot[sl];
    }
    __syncthreads();

    const char* aSrc[4];
    uint32_t aOff[4];
    {
        int colb = (tid & 7) * 16;
#pragma unroll
        for (int r = 0; r < 4; ++r) {
            int row = r * 32 + (tid >> 3);
            aSrc[r] = (const char*)hbuf + (size_t)slots[row] * (I_DIM * 2) + (colb ^ ((row & 7) << 4));
            aOff[r] = (uint32_t)(row * 128 + colb);
        }
    }
    const char* bSrc[4];
    uint32_t bOff[4];
    {
        int colb = (tid & 7) * 16;
#pragma unroll
        for (int r = 0; r < 4; ++r) {
            int row = r * 32 + (tid >> 3);
            bSrc[r] = (const char*)wd + ((size_t)e * H_DIM + (size_t)tn * 128 + row) * (I_DIM * 2)
                      + (colb ^ ((row & 7) << 4));
            bOff[r] = (uint32_t)(row * 128 + colb);
        }
    }

    const f32x4 zero = {0.f, 0.f, 0.f, 0.f};
    f32x4 acc[4][4];
#pragma unroll
    for (int i = 0; i < 4; ++i)
#pragma unroll
        for (int j = 0; j < 4; ++j) acc[i][j] = zero;

#pragma unroll
    for (int r = 0; r < 4; ++r) {
        gload_lds16(aSrc[r], &lA[0][aOff[r]]);
        gload_lds16(bSrc[r], &lB[0][bOff[r]]);
    }

    const int NT = I_DIM / BK;
    for (int kt = 0; kt < NT; ++kt) {
        const int cur = kt & 1, nxt = cur ^ 1;
        const bool pf = (kt + 1 < NT);
        if (pf) {
#pragma unroll
            for (int r = 0; r < 4; ++r) {
                gload_lds16(aSrc[r] + (kt + 1) * 128, &lA[nxt][aOff[r]]);
                gload_lds16(bSrc[r] + (kt + 1) * 128, &lB[nxt][bOff[r]]);
            }
        }
        __builtin_amdgcn_sched_barrier(0);
        if (pf) { asm volatile("s_waitcnt vmcnt(8)" ::: "memory"); }
        else    { asm volatile("s_waitcnt vmcnt(0)" ::: "memory"); }
        __builtin_amdgcn_sched_barrier(0);
        __builtin_amdgcn_s_barrier();
        __builtin_amdgcn_sched_barrier(0);
#pragma unroll
        for (int kk = 0; kk < 2; ++kk) {
            bf16x8 av[4], bv[4];
#pragma unroll
            for (int mi = 0; mi < 4; ++mi) {
                int row = wm * 64 + mi * 16 + (lane & 15);
                int byte = (row * 128 + kk * 64 + (lane >> 4) * 16) ^ ((row & 7) << 4);
                av[mi] = *(const bf16x8*)&lA[cur][byte];
            }
#pragma unroll
            for (int ni = 0; ni < 4; ++ni) {
                int row = wn * 64 + ni * 16 + (lane & 15);
                int byte = (row * 128 + kk * 64 + (lane >> 4) * 16) ^ ((row & 7) << 4);
                bv[ni] = *(const bf16x8*)&lB[cur][byte];
            }
#pragma unroll
            for (int mi = 0; mi < 4; ++mi)
#pragma unroll
                for (int ni = 0; ni < 4; ++ni)
                    acc[mi][ni] = __builtin_amdgcn_mfma_f32_16x16x32_bf16(av[mi], bv[ni], acc[mi][ni], 0, 0, 0);
        }
        __builtin_amdgcn_sched_barrier(0);
        __builtin_amdgcn_s_barrier();
        __builtin_amdgcn_sched_barrier(0);
    }

#pragma unroll
    for (int mi = 0; mi < 4; ++mi) {
#pragma unroll
        for (int ni = 0; ni < 4; ++ni) {
            int col = tn * 128 + wn * 64 + ni * 16 + (lane & 15);
#pragma unroll
            for (int r = 0; r < 4; ++r) {
                int trow = wm * 64 + mi * 16 + ((lane >> 4) << 2) + r;
                if (tm * 128 + trow < cnt) {
                    int t = slots[trow] >> 1;
                    atomicAdd(out + (size_t)t * H_DIM + col, acc[mi][ni][r] * wr[trow]);
                }
            }
        }
    }
}

extern "C" void kernel_launch(void* const* d_in, const int* in_sizes, int n_in,
                              void* d_out, int out_size, void* d_ws, size_t ws_size,
                              hipStream_t stream) {
    const float* x  = (const float*)d_in[0];
    const float* rw = (const float*)d_in[1];
    const float* Wg = (const float*)d_in[2];
    const float* Wu = (const float*)d_in[3];
    const float* Wd = (const float*)d_in[4];
    float* out = (float*)d_out;

    char* ws = (char*)d_ws;
    const size_t SZ_X = 8388608;      // xbf
    const size_t SZ_W = 46137344;     // one bf16 weight tensor
    __bf16* xbf   = (__bf16*)(ws);
    __bf16* wbf   = (__bf16*)(ws + SZ_X);                 // wg | wu | wd contiguous
    __bf16* hbuf  = (__bf16*)(ws + SZ_X + 3 * SZ_W);
    int*    list  = (int*)(ws + SZ_X + 4 * SZ_W);
    float*  wslot = (float*)(ws + SZ_X + 4 * SZ_W + 131072);
    int*    counts= (int*)(ws + SZ_X + 4 * SZ_W + 131072 + 32768);

    hipMemsetAsync(d_out, 0, (size_t)out_size * sizeof(float), stream);
    hipMemsetAsync(counts, 0, E_NUM * sizeof(int), stream);

    // blocks 0..2047: weight cvt; blocks 2048..3071: router (+x cvt)
    k_router_cvt<<<3072, 256, 0, stream>>>(x, rw, Wg, Wu, Wd, xbf, wbf, list, wslot, counts);
    k_gemm1<<<8 * 44 * 32, 256, 0, stream>>>(xbf, wbf, list, counts, hbuf);
    k_gemm2<<<8 * 8 * 32, 256, 0, stream>>>(hbuf, wbf, list, counts, wslot, out);
}

// Round 6
// 396.091 us; speedup vs baseline: 5.0668x; 1.1477x over previous
//
#include <hip/hip_runtime.h>
#include <hip/hip_bf16.h>
#include <stdint.h>

#define T_TOK 4096
#define H_DIM 1024
#define I_DIM 2816
#define E_NUM 8
#define BK 64
#define NW4 5767168           // float4 count per weight tensor (8*2816*1024/4)
#define W_ELEMS 23068672      // elements per weight tensor

typedef float f32x4 __attribute__((ext_vector_type(4)));
typedef __bf16 bf16x8 __attribute__((ext_vector_type(8)));
typedef __bf16 bf16x4 __attribute__((ext_vector_type(4)));

__device__ __forceinline__ void gload_lds16(const void* g, void* l) {
    __builtin_amdgcn_global_load_lds((const __attribute__((address_space(1))) void*)g,
                                     (__attribute__((address_space(3))) void*)l, 16, 0, 0);
}

__device__ __forceinline__ bf16x4 cvt4(float4 v) {
    bf16x4 o;
    o[0] = (__bf16)v.x; o[1] = (__bf16)v.y; o[2] = (__bf16)v.z; o[3] = (__bf16)v.w;
    return o;
}

// ---------- fused: weight cvt (blocks 0..2047) + router & x-cvt (blocks 2048..3071) ----------
__global__ __launch_bounds__(256) void k_router_cvt(const float* __restrict__ x,
                                                    const float* __restrict__ rw,
                                                    const float* __restrict__ Wg,
                                                    const float* __restrict__ Wu,
                                                    const float* __restrict__ Wd,
                                                    __bf16* __restrict__ xbf,
                                                    __bf16* __restrict__ wbf,
                                                    int* __restrict__ list,
                                                    float* __restrict__ wslot,
                                                    int* __restrict__ counts) {
    const int b = blockIdx.x;
    if (b < 2048) {
        const int stride = 2048 * 256;
        for (int i = b * 256 + threadIdx.x; i < 3 * NW4; i += stride) {
            float4 v;
            if (i < NW4)            v = ((const float4*)Wg)[i];
            else if (i < 2 * NW4)   v = ((const float4*)Wu)[i - NW4];
            else                    v = ((const float4*)Wd)[i - 2 * NW4];
            ((bf16x4*)wbf)[i] = cvt4(v);
        }
        return;
    }
    const int rb = b - 2048;
    const int tid = threadIdx.x;
    const int wid = tid >> 6, lane = tid & 63;
    const int t = rb * 4 + wid;

    float acc[E_NUM];
#pragma unroll
    for (int e = 0; e < E_NUM; ++e) acc[e] = 0.f;

    const float4* x4 = (const float4*)(x + (size_t)t * H_DIM);
    const float4* r4 = (const float4*)rw;
#pragma unroll
    for (int j = 0; j < 4; ++j) {
        float4 xv = x4[j * 64 + lane];
        ((bf16x4*)xbf)[(size_t)t * 256 + j * 64 + lane] = cvt4(xv);
#pragma unroll
        for (int e = 0; e < E_NUM; ++e) {
            float4 wv = r4[e * 256 + j * 64 + lane];
            acc[e] += xv.x * wv.x + xv.y * wv.y + xv.z * wv.z + xv.w * wv.w;
        }
    }
#pragma unroll
    for (int s = 1; s < 64; s <<= 1) {
#pragma unroll
        for (int e = 0; e < E_NUM; ++e) acc[e] += __shfl_xor(acc[e], s, 64);
    }
    if (lane == 0) {
        float best = -1e30f; int be = 0;
#pragma unroll
        for (int e = 0; e < E_NUM; ++e) if (acc[e] > best) { best = acc[e]; be = e; }
        float sec = -1e30f; int se = 0;
#pragma unroll
        for (int e = 0; e < E_NUM; ++e) if (e != be && acc[e] > sec) { sec = acc[e]; se = e; }
        float d = __expf(sec - best);
        float w1 = 1.f / (1.f + d);
        float w2 = d / (1.f + d);
        int p1 = atomicAdd(&counts[be], 1);
        list[be * T_TOK + p1] = 2 * t;
        wslot[2 * t] = w1;
        int p2 = atomicAdd(&counts[se], 1);
        list[se * T_TOK + p2] = 2 * t + 1;
        wslot[2 * t + 1] = w2;
    }
}

// ---------- GEMM1: tile 128(M)x64(N of I) dual g/u, BK=64, 256 thr / 4 waves ----------
// m97 structure: single-buffered LDS (33 KB), 2 barriers/K-step, 4 blocks/CU.
__global__ __launch_bounds__(256, 4) void k_gemm1(const __bf16* __restrict__ xbf,
                                                  const __bf16* __restrict__ wbf,
                                                  const int* __restrict__ list,
                                                  const int* __restrict__ counts,
                                                  __bf16* __restrict__ hbuf) {
    __shared__ __attribute__((aligned(16))) unsigned char lA[128 * 128];
    __shared__ __attribute__((aligned(16))) unsigned char lBg[64 * 128];
    __shared__ __attribute__((aligned(16))) unsigned char lBu[64 * 128];
    __shared__ int slots[128];

    const __bf16* wg = wbf;
    const __bf16* wu = wbf + (size_t)W_ELEMS;

    const int lid = blockIdx.x;
    const int e = lid & 7;          // expert pinned to XCD
    const int seq = lid >> 3;
    const int tn = seq >> 5;        // 44 tiles of 64 cols
    const int tm = seq & 31;        // tm inner: B panel shared by concurrent siblings
    const int cnt = counts[e];
    if (tm * 128 >= cnt) return;
    const int tid = threadIdx.x;
    const int lane = tid & 63;
    const int wid = tid >> 6;
    const int wm = wid >> 1;        // 2 x 64 rows
    const int wn = wid & 1;         // 2 x 32 cols

    if (tid < 128) {
        int p = tm * 128 + tid;
        slots[tid] = list[e * T_TOK + (p < cnt ? p : cnt - 1)];
    }
    __syncthreads();

    // A staging: 128 rows x 128B, 4 gloads/thread (source pre-swizzled, LDS linear)
    const char* aSrc[4];
    uint32_t aOff[4];
    {
        int colb = (tid & 7) * 16;
#pragma unroll
        for (int r = 0; r < 4; ++r) {
            int row = r * 32 + (tid >> 3);
            int tok = slots[row] >> 1;
            aSrc[r] = (const char*)xbf + (size_t)tok * (H_DIM * 2) + (colb ^ ((row & 7) << 4));
            aOff[r] = (uint32_t)(row * 128 + colb);
        }
    }
    // B staging: 64 rows x 128B per matrix, 2 gloads/thread each
    const char* bgSrc[2];
    const char* buSrc[2];
    uint32_t bOff[2];
    {
        int colb = (tid & 7) * 16;
#pragma unroll
        for (int r = 0; r < 2; ++r) {
            int row = r * 32 + (tid >> 3);
            size_t gr = ((size_t)e * I_DIM + (size_t)tn * 64 + row) * (H_DIM * 2) + (colb ^ ((row & 7) << 4));
            bgSrc[r] = (const char*)wg + gr;
            buSrc[r] = (const char*)wu + gr;
            bOff[r] = (uint32_t)(row * 128 + colb);
        }
    }

    const f32x4 zero = {0.f, 0.f, 0.f, 0.f};
    f32x4 accg[4][2], accu[4][2];
#pragma unroll
    for (int i = 0; i < 4; ++i)
#pragma unroll
        for (int j = 0; j < 2; ++j) { accg[i][j] = zero; accu[i][j] = zero; }

    const int NT = H_DIM / BK;
    for (int kt = 0; kt < NT; ++kt) {
        if (kt > 0) __syncthreads();   // WAR: all waves done reading previous tile
        // stage tile kt (8 gloads/thread)
#pragma unroll
        for (int r = 0; r < 4; ++r) gload_lds16(aSrc[r] + kt * 128, &lA[aOff[r]]);
#pragma unroll
        for (int r = 0; r < 2; ++r) {
            gload_lds16(bgSrc[r] + kt * 128, &lBg[bOff[r]]);
            gload_lds16(buSrc[r] + kt * 128, &lBu[bOff[r]]);
        }
        __syncthreads();               // implicit vmcnt(0) drain + barrier (m97 pattern)
        __builtin_amdgcn_s_setprio(1);
#pragma unroll
        for (int kk = 0; kk < 2; ++kk) {
            bf16x8 av[4], bg[2], bu[2];
#pragma unroll
            for (int mi = 0; mi < 4; ++mi) {
                int row = wm * 64 + mi * 16 + (lane & 15);
                int byte = (row * 128 + kk * 64 + (lane >> 4) * 16) ^ ((row & 7) << 4);
                av[mi] = *(const bf16x8*)&lA[byte];
            }
#pragma unroll
            for (int ni = 0; ni < 2; ++ni) {
                int row = wn * 32 + ni * 16 + (lane & 15);
                int byte = (row * 128 + kk * 64 + (lane >> 4) * 16) ^ ((row & 7) << 4);
                bg[ni] = *(const bf16x8*)&lBg[byte];
                bu[ni] = *(const bf16x8*)&lBu[byte];
            }
#pragma unroll
            for (int mi = 0; mi < 4; ++mi)
#pragma unroll
                for (int ni = 0; ni < 2; ++ni) {
                    accg[mi][ni] = __builtin_amdgcn_mfma_f32_16x16x32_bf16(av[mi], bg[ni], accg[mi][ni], 0, 0, 0);
                    accu[mi][ni] = __builtin_amdgcn_mfma_f32_16x16x32_bf16(av[mi], bu[ni], accu[mi][ni], 0, 0, 0);
                }
        }
        __builtin_amdgcn_s_setprio(0);
    }

#pragma unroll
    for (int mi = 0; mi < 4; ++mi) {
#pragma unroll
        for (int ni = 0; ni < 2; ++ni) {
            int col = tn * 64 + wn * 32 + ni * 16 + (lane & 15);
#pragma unroll
            for (int r = 0; r < 4; ++r) {
                int trow = wm * 64 + mi * 16 + ((lane >> 4) << 2) + r;
                if (tm * 128 + trow < cnt) {
                    float g = accg[mi][ni][r];
                    float u = accu[mi][ni][r];
                    float hv = (g / (1.f + __expf(-g))) * u;
                    hbuf[(size_t)slots[trow] * I_DIM + col] = (__bf16)hv;
                }
            }
        }
    }
}

// ---------- GEMM2: tile 128(M)x128(N of H), BK=64, K-split x2, 256 thr / 4 waves ----------
__global__ __launch_bounds__(256, 4) void k_gemm2(const __bf16* __restrict__ hbuf,
                                                  const __bf16* __restrict__ wbf,
                                                  const int* __restrict__ list,
                                                  const int* __restrict__ counts,
                                                  const float* __restrict__ wslot,
                                                  float* __restrict__ out) {
    __shared__ __attribute__((aligned(16))) unsigned char lA[128 * 128];
    __shared__ __attribute__((aligned(16))) unsigned char lB[128 * 128];
    __shared__ int slots[128];
    __shared__ float wr[128];

    const __bf16* wd = wbf + 2 * (size_t)W_ELEMS;

    const int lid = blockIdx.x;
    const int e = lid & 7;
    const int seq = lid >> 3;           // 0..511
    const int tn = seq & 7;             // tn inner: A panel shared by concurrent siblings
    const int kh = (seq >> 3) & 1;      // K-half
    const int tm = seq >> 4;            // 0..31
    const int cnt = counts[e];
    if (tm * 128 >= cnt) return;
    const int tid = threadIdx.x;
    const int lane = tid & 63;
    const int wid = tid >> 6;
    const int wm = wid >> 1;            // 2 x 64 rows
    const int wn = wid & 1;             // 2 x 64 cols

    if (tid < 128) {
        int p = tm * 128 + tid;
        int sl = list[e * T_TOK + (p < cnt ? p : cnt - 1)];
        slots[tid] = sl;
        wr[tid] = wslot[sl];
    }
    __syncthreads();

    const int NTH = (I_DIM / BK) / 2;   // 22 K-steps per half
    const int kbase = kh * NTH;         // in units of BK

    const char* aSrc[4];
    uint32_t aOff[4];
    {
        int colb = (tid & 7) * 16;
#pragma unroll
        for (int r = 0; r < 4; ++r) {
            int row = r * 32 + (tid >> 3);
            aSrc[r] = (const char*)hbuf + (size_t)slots[row] * (I_DIM * 2)
                      + (size_t)kbase * 128 + (colb ^ ((row & 7) << 4));
            aOff[r] = (uint32_t)(row * 128 + colb);
        }
    }
    const char* bSrc[4];
    uint32_t bOff[4];
    {
        int colb = (tid & 7) * 16;
#pragma unroll
        for (int r = 0; r < 4; ++r) {
            int row = r * 32 + (tid >> 3);
            bSrc[r] = (const char*)wd + ((size_t)e * H_DIM + (size_t)tn * 128 + row) * (I_DIM * 2)
                      + (size_t)kbase * 128 + (colb ^ ((row & 7) << 4));
            bOff[r] = (uint32_t)(row * 128 + colb);
        }
    }

    const f32x4 zero = {0.f, 0.f, 0.f, 0.f};
    f32x4 acc[4][4];
#pragma unroll
    for (int i = 0; i < 4; ++i)
#pragma unroll
        for (int j = 0; j < 4; ++j) acc[i][j] = zero;

    for (int kt = 0; kt < NTH; ++kt) {
        if (kt > 0) __syncthreads();
#pragma unroll
        for (int r = 0; r < 4; ++r) {
            gload_lds16(aSrc[r] + kt * 128, &lA[aOff[r]]);
            gload_lds16(bSrc[r] + kt * 128, &lB[bOff[r]]);
        }
        __syncthreads();
        __builtin_amdgcn_s_setprio(1);
#pragma unroll
        for (int kk = 0; kk < 2; ++kk) {
            bf16x8 av[4], bv[4];
#pragma unroll
            for (int mi = 0; mi < 4; ++mi) {
                int row = wm * 64 + mi * 16 + (lane & 15);
                int byte = (row * 128 + kk * 64 + (lane >> 4) * 16) ^ ((row & 7) << 4);
                av[mi] = *(const bf16x8*)&lA[byte];
            }
#pragma unroll
            for (int ni = 0; ni < 4; ++ni) {
                int row = wn * 64 + ni * 16 + (lane & 15);
                int byte = (row * 128 + kk * 64 + (lane >> 4) * 16) ^ ((row & 7) << 4);
                bv[ni] = *(const bf16x8*)&lB[byte];
            }
#pragma unroll
            for (int mi = 0; mi < 4; ++mi)
#pragma unroll
                for (int ni = 0; ni < 4; ++ni)
                    acc[mi][ni] = __builtin_amdgcn_mfma_f32_16x16x32_bf16(av[mi], bv[ni], acc[mi][ni], 0, 0, 0);
        }
        __builtin_amdgcn_s_setprio(0);
    }

#pragma unroll
    for (int mi = 0; mi < 4; ++mi) {
#pragma unroll
        for (int ni = 0; ni < 4; ++ni) {
            int col = tn * 128 + wn * 64 + ni * 16 + (lane & 15);
#pragma unroll
            for (int r = 0; r < 4; ++r) {
                int trow = wm * 64 + mi * 16 + ((lane >> 4) << 2) + r;
                if (tm * 128 + trow < cnt) {
                    int t = slots[trow] >> 1;
                    atomicAdd(out + (size_t)t * H_DIM + col, acc[mi][ni][r] * wr[trow]);
                }
            }
        }
    }
}

extern "C" void kernel_launch(void* const* d_in, const int* in_sizes, int n_in,
                              void* d_out, int out_size, void* d_ws, size_t ws_size,
                              hipStream_t stream) {
    const float* x  = (const float*)d_in[0];
    const float* rw = (const float*)d_in[1];
    const float* Wg = (const float*)d_in[2];
    const float* Wu = (const float*)d_in[3];
    const float* Wd = (const float*)d_in[4];
    float* out = (float*)d_out;

    char* ws = (char*)d_ws;
    const size_t SZ_X = 8388608;      // xbf
    const size_t SZ_W = 46137344;     // one bf16 weight tensor
    __bf16* xbf   = (__bf16*)(ws);
    __bf16* wbf   = (__bf16*)(ws + SZ_X);                 // wg | wu | wd contiguous
    __bf16* hbuf  = (__bf16*)(ws + SZ_X + 3 * SZ_W);
    int*    list  = (int*)(ws + SZ_X + 4 * SZ_W);
    float*  wslot = (float*)(ws + SZ_X + 4 * SZ_W + 131072);
    int*    counts= (int*)(ws + SZ_X + 4 * SZ_W + 131072 + 32768);

    hipMemsetAsync(d_out, 0, (size_t)out_size * sizeof(float), stream);
    hipMemsetAsync(counts, 0, E_NUM * sizeof(int), stream);

    k_router_cvt<<<3072, 256, 0, stream>>>(x, rw, Wg, Wu, Wd, xbf, wbf, list, wslot, counts);
    k_gemm1<<<8 * 44 * 32, 256, 0, stream>>>(xbf, wbf, list, counts, hbuf);
    k_gemm2<<<8 * 8 * 2 * 32, 256, 0, stream>>>(hbuf, wbf, list, counts, wslot, out);
}